// Round 2
// baseline (958.927 us; speedup 1.0000x reference)
//
#include <hip/hip_runtime.h>
#include <math.h>

#define SEQL 256
#define DM   256
#define NH   8
#define DKH  32
#define BSZ  4
#define NKN  16

// ---------------- reduction helpers (256-thread block = 4 waves) ----------------

__device__ __forceinline__ float wave_max(float v) {
#pragma unroll
  for (int o = 32; o > 0; o >>= 1) v = fmaxf(v, __shfl_xor(v, o));
  return v;
}
__device__ __forceinline__ float wave_sum(float v) {
#pragma unroll
  for (int o = 32; o > 0; o >>= 1) v += __shfl_xor(v, o);
  return v;
}
__device__ __forceinline__ float block_max(float v, float* red) {
  v = wave_max(v);
  __syncthreads();
  if ((threadIdx.x & 63) == 0) red[threadIdx.x >> 6] = v;
  __syncthreads();
  return fmaxf(fmaxf(red[0], red[1]), fmaxf(red[2], red[3]));
}
__device__ __forceinline__ float block_sum(float v, float* red) {
  v = wave_sum(v);
  __syncthreads();
  if ((threadIdx.x & 63) == 0) red[threadIdx.x >> 6] = v;
  __syncthreads();
  return (red[0] + red[1]) + (red[2] + red[3]);
}
// inclusive scan across 256 threads; also returns grand total
__device__ __forceinline__ float block_scan_incl(float v, float* red, float* total) {
  const int lane = threadIdx.x & 63, w = threadIdx.x >> 6;
#pragma unroll
  for (int o = 1; o < 64; o <<= 1) {
    float t = __shfl_up(v, o);
    if (lane >= o) v += t;
  }
  __syncthreads();
  if (lane == 63) red[w] = v;
  __syncthreads();
  float add = 0.f;
  if (w > 0) add += red[0];
  if (w > 1) add += red[1];
  if (w > 2) add += red[2];
  *total = (red[0] + red[1]) + (red[2] + red[3]);
  return v + add;
}

// ---------------- GEMM: C[M,256] = A[M,256] @ W[256,256] + bias ----------------
// 64x64 tile, BK=16, 256 threads, 4x4 microtile per thread.
__global__ __launch_bounds__(256) void dt_gemm_bias(const float* __restrict__ A,
                                                    const float* __restrict__ W,
                                                    const float* __restrict__ bias,
                                                    float* __restrict__ C, int M) {
  __shared__ float As[16][68];  // [k][m]
  __shared__ float Bs[16][68];  // [k][n]
  const int tid = threadIdx.x;
  const int bm = blockIdx.x * 64, bn = blockIdx.y * 64;
  const int tc = tid & 15, tr = tid >> 4;
  float acc[4][4] = {};
  for (int k0 = 0; k0 < DM; k0 += 16) {
    {
      const int m = tid >> 2, kq = tid & 3;
      int row = bm + m; row = row < M ? row : (M - 1);
      const float4 v = *reinterpret_cast<const float4*>(&A[(size_t)row * DM + k0 + kq * 4]);
      As[kq * 4 + 0][m] = v.x; As[kq * 4 + 1][m] = v.y;
      As[kq * 4 + 2][m] = v.z; As[kq * 4 + 3][m] = v.w;
    }
    {
      const int k = tid >> 4, nq = tid & 15;
      const float4 v = *reinterpret_cast<const float4*>(&W[(size_t)(k0 + k) * DM + bn + nq * 4]);
      *reinterpret_cast<float4*>(&Bs[k][nq * 4]) = v;
    }
    __syncthreads();
#pragma unroll
    for (int k = 0; k < 16; ++k) {
      float a[4], b[4];
#pragma unroll
      for (int i = 0; i < 4; ++i) a[i] = As[k][tr * 4 + i];
#pragma unroll
      for (int j = 0; j < 4; ++j) b[j] = Bs[k][tc * 4 + j];
#pragma unroll
      for (int i = 0; i < 4; ++i)
#pragma unroll
        for (int j = 0; j < 4; ++j) acc[i][j] = fmaf(a[i], b[j], acc[i][j]);
    }
    __syncthreads();
  }
#pragma unroll
  for (int i = 0; i < 4; ++i) {
    const int row = bm + tr * 4 + i;
    if (row >= M) continue;
    float4 o;
    o.x = acc[i][0] + bias[bn + tc * 4 + 0];
    o.y = acc[i][1] + bias[bn + tc * 4 + 1];
    o.z = acc[i][2] + bias[bn + tc * 4 + 2];
    o.w = acc[i][3] + bias[bn + tc * 4 + 3];
    *reinterpret_cast<float4*>(&C[(size_t)row * DM + bn + tc * 4]) = o;
  }
}

// ---------------- blocks 1-3 scores: S[bh,i,j] = Q[i]·Q[j] / sqrt(dk) ----------------
__global__ __launch_bounds__(256) void dt_scores_nt(const float* __restrict__ Qp,
                                                    float* __restrict__ S) {
  const int bz = blockIdx.z;       // b*8+h
  const int b = bz >> 3, h = bz & 7;
  const float* Q = Qp + (size_t)b * SEQL * DM + h * DKH;
  __shared__ float Qs[16][33], Ks[16][33];
  const int tid = threadIdx.x;
  const int tj = tid & 15, ti = tid >> 4;
  const int i0 = blockIdx.x * 16, j0 = blockIdx.y * 16;
  const int r = tid >> 5, c = tid & 31;
  Qs[r][c]     = Q[(size_t)(i0 + r) * DM + c];
  Qs[r + 8][c] = Q[(size_t)(i0 + 8 + r) * DM + c];
  Ks[r][c]     = Q[(size_t)(j0 + r) * DM + c];
  Ks[r + 8][c] = Q[(size_t)(j0 + 8 + r) * DM + c];
  __syncthreads();
  float acc = 0.f;
#pragma unroll
  for (int k = 0; k < DKH; ++k) acc = fmaf(Qs[ti][k], Ks[tj][k], acc);
  S[((size_t)bz * SEQL + i0 + ti) * SEQL + j0 + tj] = acc * 0.17677669529663687f;
}

// ---------------- block 4 base scores: s0[b,nk,h,j] (independent of query row) ----------------
__global__ __launch_bounds__(256) void dt_scores4(const float* __restrict__ Q4h,
                                                  const float* __restrict__ Kp,
                                                  float* __restrict__ S0) {
  const int idx = blockIdx.x * 256 + threadIdx.x;  // ((b*16+nk)*8+h)*256 + j
  const int j = idx & 255;
  const int h = (idx >> 8) & 7;
  const int nk = (idx >> 11) & 15;
  const int b = idx >> 15;
  const float* q = Q4h + nk * DM + h * DKH;
  const float* k = Kp + ((size_t)(b * SEQL + j)) * DM + h * DKH;
  float acc = 0.f;
#pragma unroll
  for (int c = 0; c < DKH; ++c) acc = fmaf(q[c], k[c], acc);
  S0[idx] = acc * 0.17677669529663687f;
}

// ---------------- decay-softmax, blocks 1-3 (mask j<=i, no maxout) ----------------
// one 256-thread block per row; row = (b*8+h)*256 + i
__global__ __launch_bounds__(256) void dt_softmax13(const float* __restrict__ S,
                                                    float* __restrict__ P,
                                                    const float* __restrict__ gam) {
  __shared__ float red[4];
  const int row = blockIdx.x;
  const int i = row & 255;
  const int h = (row >> 8) & 7;
  const int j = threadIdx.x;
  const float s = S[(size_t)row * SEQL + j];
  const bool m = (j <= i);
  const float x = m ? s : -1e32f;
  const float mx = block_max(x, red);
  const float e = expf(x - mx);
  const float sum = block_sum(e, red);
  const float sm = e / sum;
  float T;
  const float cum = block_scan_incl(sm, red, &T);
  const float pos = fabsf((float)(i - j));
  float dd = (T - cum) * pos;
  dd = dd < 0.f ? 0.f : dd;
  const float dist = sqrtf(dd);
  const float g = -fabsf(gam[h]);
  float eff = expf(dist * g);
  eff = fminf(fmaxf(eff, 1e-5f), 1e5f);
  const float y = s * eff;
  const float x2 = m ? y : -1e32f;
  const float mx2 = block_max(x2, red);
  const float e2 = expf(x2 - mx2);
  const float sum2 = block_sum(e2, red);
  const float p = m ? (e2 / sum2) : 0.f;
  P[(size_t)row * SEQL + j] = p;
}

// ---------------- decay-softmax, block 4 (mask j<i, maxout; scores broadcast over i) ----------------
// row = ((b*16+nk)*8+h)*256 + i ; writes k_scores[b,h,i,nk,j]
__global__ __launch_bounds__(256) void dt_softmax4(const float* __restrict__ S0,
                                                   float* __restrict__ KS,
                                                   const float* __restrict__ gam) {
  __shared__ float red[4];
  const int row = blockIdx.x;
  const int i = row & 255;
  const int h = (row >> 8) & 7;
  const int nk = (row >> 11) & 15;
  const int b = row >> 15;
  const int j = threadIdx.x;
  const float s = S0[(size_t)(row & ~255) + j];  // same base row for every i
  const bool m = (j < i);
  const float x = m ? s : -1e32f;
  const float mx = block_max(x, red);
  const float e = expf(x - mx);
  const float sum = block_sum(e, red);
  const float sm = e / sum;
  float T;
  const float cum = block_scan_incl(sm, red, &T);
  const float pos = fabsf((float)(i - j));
  float dd = (T - cum) * pos;
  dd = dd < 0.f ? 0.f : dd;
  const float dist = sqrtf(dd);
  const float g = -fabsf(gam[h]);
  float eff = expf(dist * g);
  eff = fminf(fmaxf(eff, 1e-5f), 1e5f);
  const float y = s * eff;
  const float x2 = m ? y : -1e32f;
  const float mx2 = block_max(x2, red);
  const float e2 = expf(x2 - mx2);
  const float sum2 = block_sum(e2, red);
  float p = m ? (e2 / sum2) : 0.f;
  const float mx3 = block_max(p, red);
  const float scale = fminf(1.f / (mx3 + 1e-8f), 5.f);
  p *= scale;
  KS[((((size_t)(b * NH + h)) * SEQL + i) * NKN + nk) * SEQL + j] = p;
}

// ---------------- PV, blocks 1-3: O[b,i,h*32+c] = sum_j P[bh,i,j]*V[b,j,h*32+c] ----------------
__global__ __launch_bounds__(256) void dt_pv13(const float* __restrict__ P,
                                               const float* __restrict__ Vp,
                                               float* __restrict__ O) {
  __shared__ float Ps[32][33];
  __shared__ float Vs[32][33];
  const int bh = blockIdx.y, b = bh >> 3, h = bh & 7;
  const int i0 = blockIdx.x * 32;
  const int tid = threadIdx.x;
  const int c = tid & 31, ir = tid >> 5;
  float acc[4] = {0.f, 0.f, 0.f, 0.f};
  const float* Prow = P + ((size_t)bh * SEQL + i0) * SEQL;
  const float* Vbase = Vp + (size_t)b * SEQL * DM + h * DKH;
  for (int j0 = 0; j0 < SEQL; j0 += 32) {
#pragma unroll
    for (int k = 0; k < 4; ++k) {
      Ps[ir + k * 8][c] = Prow[(size_t)(ir + k * 8) * SEQL + j0 + c];
      Vs[ir + k * 8][c] = Vbase[(size_t)(j0 + ir + k * 8) * DM + c];
    }
    __syncthreads();
#pragma unroll
    for (int jj = 0; jj < 32; ++jj) {
      const float v = Vs[jj][c];
#pragma unroll
      for (int k = 0; k < 4; ++k) acc[k] = fmaf(Ps[ir + k * 8][jj], v, acc[k]);
    }
    __syncthreads();
  }
#pragma unroll
  for (int k = 0; k < 4; ++k)
    O[((size_t)(b * SEQL + i0 + ir + k * 8)) * DM + h * DKH + c] = acc[k];
}

// ---------------- PV, block 4: reads k_scores[b,h,i,nk,j] from d_out ----------------
__global__ __launch_bounds__(256) void dt_pv4(const float* __restrict__ KS,
                                              const float* __restrict__ Vp,
                                              float* __restrict__ O) {
  __shared__ float Ps[32][33];
  __shared__ float Vs[32][33];
  const int z = blockIdx.y;  // (b*16+nk)*8+h
  const int h = z & 7, nk = (z >> 3) & 15, b = z >> 7;
  const int i0 = blockIdx.x * 32;
  const int tid = threadIdx.x;
  const int c = tid & 31, ir = tid >> 5;
  float acc[4] = {0.f, 0.f, 0.f, 0.f};
  const float* Pbase = KS + ((size_t)(b * NH + h)) * SEQL * NKN * SEQL + (size_t)nk * SEQL;
  const float* Vbase = Vp + (size_t)b * SEQL * DM + h * DKH;
  for (int j0 = 0; j0 < SEQL; j0 += 32) {
#pragma unroll
    for (int k = 0; k < 4; ++k) {
      const int i = i0 + ir + k * 8;
      Ps[ir + k * 8][c] = Pbase[(size_t)i * (NKN * SEQL) + j0 + c];
      Vs[ir + k * 8][c] = Vbase[(size_t)(j0 + ir + k * 8) * DM + c];
    }
    __syncthreads();
#pragma unroll
    for (int jj = 0; jj < 32; ++jj) {
      const float v = Vs[jj][c];
#pragma unroll
      for (int k = 0; k < 4; ++k) acc[k] = fmaf(Ps[ir + k * 8][jj], v, acc[k]);
    }
    __syncthreads();
  }
  const int bnk = (z >> 3);
#pragma unroll
  for (int k = 0; k < 4; ++k)
    O[((size_t)(bnk * SEQL + i0 + ir + k * 8)) * DM + h * DKH + c] = acc[k];
}

// ---------------- residual + LayerNorm, blocks 1-3 ----------------
__global__ __launch_bounds__(256) void dt_ln_res(const float* __restrict__ X,
                                                 const float* __restrict__ Y,
                                                 const float* __restrict__ g,
                                                 const float* __restrict__ bb,
                                                 float* __restrict__ Z) {
  __shared__ float red[4];
  const int row = blockIdx.x;
  const int j = threadIdx.x;
  const float x = X[(size_t)row * DM + j] + Y[(size_t)row * DM + j];
  const float mean = block_sum(x, red) * (1.f / 256.f);
  const float d = x - mean;
  const float var = block_sum(d * d, red) * (1.f / 256.f);
  Z[(size_t)row * DM + j] = d / sqrtf(var + 1e-5f) * g[j] + bb[j];
}

// ---------------- residual + LayerNorm, block 4 (residual = know_params, transposed z write) ----------------
__global__ __launch_bounds__(256) void dt_ln4(const float* __restrict__ know,
                                              const float* __restrict__ Y,
                                              const float* __restrict__ g,
                                              const float* __restrict__ bb,
                                              float* __restrict__ Z) {
  __shared__ float red[4];
  const int row = blockIdx.x;  // (b*16+nk)*256 + i
  const int i = row & 255;
  const int nk = (row >> 8) & 15;
  const int b = row >> 12;
  const int j = threadIdx.x;
  const float x = know[(size_t)nk * DM + j] + Y[(size_t)row * DM + j];
  const float mean = block_sum(x, red) * (1.f / 256.f);
  const float d = x - mean;
  const float var = block_sum(d * d, red) * (1.f / 256.f);
  const float val = d / sqrtf(var + 1e-5f) * g[j] + bb[j];
  Z[((size_t)(b * SEQL + i)) * (NKN * DM) + (size_t)nk * DM + j] = val;
}

// ---------------- launcher ----------------
extern "C" void kernel_launch(void* const* d_in, const int* in_sizes, int n_in,
                              void* d_out, int out_size, void* d_ws, size_t ws_size,
                              hipStream_t stream) {
  (void)in_sizes; (void)n_in; (void)out_size; (void)ws_size;
  const float* q_emb = (const float*)d_in[0];
  const float* s_emb = (const float*)d_in[1];
  const float* know  = (const float*)d_in[3];
  const float* Wq1 = (const float*)d_in[4],  *bq1 = (const float*)d_in[5];
  const float* Wv1 = (const float*)d_in[6],  *bv1 = (const float*)d_in[7];
  const float* Wo1 = (const float*)d_in[8],  *bo1 = (const float*)d_in[9];
  const float* gam1 = (const float*)d_in[10], *lng1 = (const float*)d_in[11], *lnb1 = (const float*)d_in[12];
  const float* Wq2 = (const float*)d_in[13], *bq2 = (const float*)d_in[14];
  const float* Wv2 = (const float*)d_in[15], *bv2 = (const float*)d_in[16];
  const float* Wo2 = (const float*)d_in[17], *bo2 = (const float*)d_in[18];
  const float* gam2 = (const float*)d_in[19], *lng2 = (const float*)d_in[20], *lnb2 = (const float*)d_in[21];
  const float* Wq3 = (const float*)d_in[22], *bq3 = (const float*)d_in[23];
  const float* Wv3 = (const float*)d_in[24], *bv3 = (const float*)d_in[25];
  const float* Wo3 = (const float*)d_in[26], *bo3 = (const float*)d_in[27];
  const float* gam3 = (const float*)d_in[28], *lng3 = (const float*)d_in[29], *lnb3 = (const float*)d_in[30];
  const float* Wq4 = (const float*)d_in[31], *bq4 = (const float*)d_in[32];
  const float* Wk4 = (const float*)d_in[33], *bk4 = (const float*)d_in[34];
  const float* Wv4 = (const float*)d_in[35], *bv4 = (const float*)d_in[36];
  const float* Wo4 = (const float*)d_in[37], *bo4 = (const float*)d_in[38];
  const float* gam4 = (const float*)d_in[39], *lng4 = (const float*)d_in[40], *lnb4 = (const float*)d_in[41];

  // workspace layout (floats): total ~8.26M floats = ~31.5 MB
  float* ws = (float*)d_ws;
  float* Qp  = ws;                   // 262144  (also Kp4)
  float* Vp  = Qp + 262144;          // 262144  (also Vp4)
  float* S   = Vp + 262144;          // 2097152 (scores blocks 1-3)
  float* O   = S + 2097152;          // 262144
  float* OW  = O + 262144;           // 262144
  float* hq  = OW + 262144;          // 262144
  float* hs  = hq + 262144;          // 262144
  float* pbf = hs + 262144;          // 262144
  float* Q4h = pbf + 262144;         // 4096
  float* S0  = Q4h + 4096;           // 131072
  float* OW4 = S0 + 131072;          // 4194304

  float* zout = (float*)d_out;       // 4*256*4096
  float* qsc  = zout + 4194304;      // 4*8*256*256
  float* ksc  = qsc + 2097152;       // 4*8*256*16*256
  float* O4   = zout;                // reuse z region as block-4 attn-out scratch
                                     // (dt_ln4 fully rewrites zout from OW4 at the end)

  const dim3 thr(256);

  // ---- block 1 (q_emb -> hq) ----
  dt_gemm_bias<<<dim3(16, 4), thr, 0, stream>>>(q_emb, Wq1, bq1, Qp, 1024);
  dt_gemm_bias<<<dim3(16, 4), thr, 0, stream>>>(q_emb, Wv1, bv1, Vp, 1024);
  dt_scores_nt<<<dim3(16, 16, 32), thr, 0, stream>>>(Qp, S);
  dt_softmax13<<<dim3(8192), thr, 0, stream>>>(S, S, gam1);
  dt_pv13<<<dim3(8, 32), thr, 0, stream>>>(S, Vp, O);
  dt_gemm_bias<<<dim3(16, 4), thr, 0, stream>>>(O, Wo1, bo1, OW, 1024);
  dt_ln_res<<<dim3(1024), thr, 0, stream>>>(q_emb, OW, lng1, lnb1, hq);

  // ---- block 2 (s_emb -> hs) ----
  dt_gemm_bias<<<dim3(16, 4), thr, 0, stream>>>(s_emb, Wq2, bq2, Qp, 1024);
  dt_gemm_bias<<<dim3(16, 4), thr, 0, stream>>>(s_emb, Wv2, bv2, Vp, 1024);
  dt_scores_nt<<<dim3(16, 16, 32), thr, 0, stream>>>(Qp, S);
  dt_softmax13<<<dim3(8192), thr, 0, stream>>>(S, S, gam2);
  dt_pv13<<<dim3(8, 32), thr, 0, stream>>>(S, Vp, O);
  dt_gemm_bias<<<dim3(16, 4), thr, 0, stream>>>(O, Wo2, bo2, OW, 1024);
  dt_ln_res<<<dim3(1024), thr, 0, stream>>>(s_emb, OW, lng2, lnb2, hs);

  // ---- block 3 (q=k=hq, v=hs -> pbf; scores -> q_scores out) ----
  dt_gemm_bias<<<dim3(16, 4), thr, 0, stream>>>(hq, Wq3, bq3, Qp, 1024);
  dt_gemm_bias<<<dim3(16, 4), thr, 0, stream>>>(hs, Wv3, bv3, Vp, 1024);
  dt_scores_nt<<<dim3(16, 16, 32), thr, 0, stream>>>(Qp, S);
  dt_softmax13<<<dim3(8192), thr, 0, stream>>>(S, qsc, gam3);
  dt_pv13<<<dim3(8, 32), thr, 0, stream>>>(qsc, Vp, O);
  dt_gemm_bias<<<dim3(16, 4), thr, 0, stream>>>(O, Wo3, bo3, OW, 1024);
  dt_ln_res<<<dim3(1024), thr, 0, stream>>>(hq, OW, lng3, lnb3, pbf);

  // ---- block 4 (query = know broadcast; k from hq; v from pbf) ----
  dt_gemm_bias<<<dim3(1, 4),  thr, 0, stream>>>(know, Wq4, bq4, Q4h, 16);
  dt_gemm_bias<<<dim3(16, 4), thr, 0, stream>>>(hq,  Wk4, bk4, Qp, 1024);   // Kp4
  dt_gemm_bias<<<dim3(16, 4), thr, 0, stream>>>(pbf, Wv4, bv4, Vp, 1024);   // Vp4
  dt_scores4<<<dim3(512), thr, 0, stream>>>(Q4h, Qp, S0);
  dt_softmax4<<<dim3(131072), thr, 0, stream>>>(S0, ksc, gam4);
  dt_pv4<<<dim3(8, 512), thr, 0, stream>>>(ksc, Vp, O4);
  dt_gemm_bias<<<dim3(256, 4), thr, 0, stream>>>(O4, Wo4, bo4, OW4, 16384);
  dt_ln4<<<dim3(16384), thr, 0, stream>>>(know, OW4, lng4, lnb4, zout);
}

// Round 3
// 720.264 us; speedup vs baseline: 1.3314x; 1.3314x over previous
//
#include <hip/hip_runtime.h>
#include <math.h>

#define SEQL 256
#define DM   256
#define NH   8
#define DKH  32
#define BSZ  4
#define NKN  16

// ---------------- wave (64-lane) helpers ----------------
__device__ __forceinline__ float wave_red_sum(float v) {
#pragma unroll
  for (int o = 32; o > 0; o >>= 1) v += __shfl_xor(v, o);
  return v;
}
__device__ __forceinline__ float wave_red_max(float v) {
#pragma unroll
  for (int o = 32; o > 0; o >>= 1) v = fmaxf(v, __shfl_xor(v, o));
  return v;
}
// inclusive scan across 64 lanes
__device__ __forceinline__ float wave_incl_scan(float v) {
  const int lane = threadIdx.x & 63;
#pragma unroll
  for (int o = 1; o < 64; o <<= 1) {
    float u = __shfl_up(v, o);
    if (lane >= o) v += u;
  }
  return v;
}

// ---------------- GEMM: C[M,256] = A[M,256] @ W[256,256] + bias ----------------
__global__ __launch_bounds__(256) void dt_gemm_bias(const float* __restrict__ A,
                                                    const float* __restrict__ W,
                                                    const float* __restrict__ bias,
                                                    float* __restrict__ C, int M) {
  __shared__ float As[16][68];
  __shared__ float Bs[16][68];
  const int tid = threadIdx.x;
  const int bm = blockIdx.x * 64, bn = blockIdx.y * 64;
  const int tc = tid & 15, tr = tid >> 4;
  float acc[4][4] = {};
  for (int k0 = 0; k0 < DM; k0 += 16) {
    {
      const int m = tid >> 2, kq = tid & 3;
      int row = bm + m; row = row < M ? row : (M - 1);
      const float4 v = *reinterpret_cast<const float4*>(&A[(size_t)row * DM + k0 + kq * 4]);
      As[kq * 4 + 0][m] = v.x; As[kq * 4 + 1][m] = v.y;
      As[kq * 4 + 2][m] = v.z; As[kq * 4 + 3][m] = v.w;
    }
    {
      const int k = tid >> 4, nq = tid & 15;
      const float4 v = *reinterpret_cast<const float4*>(&W[(size_t)(k0 + k) * DM + bn + nq * 4]);
      *reinterpret_cast<float4*>(&Bs[k][nq * 4]) = v;
    }
    __syncthreads();
#pragma unroll
    for (int k = 0; k < 16; ++k) {
      float a[4], b[4];
#pragma unroll
      for (int i = 0; i < 4; ++i) a[i] = As[k][tr * 4 + i];
#pragma unroll
      for (int j = 0; j < 4; ++j) b[j] = Bs[k][tc * 4 + j];
#pragma unroll
      for (int i = 0; i < 4; ++i)
#pragma unroll
        for (int j = 0; j < 4; ++j) acc[i][j] = fmaf(a[i], b[j], acc[i][j]);
    }
    __syncthreads();
  }
#pragma unroll
  for (int i = 0; i < 4; ++i) {
    const int row = bm + tr * 4 + i;
    if (row >= M) continue;
    float4 o;
    o.x = acc[i][0] + bias[bn + tc * 4 + 0];
    o.y = acc[i][1] + bias[bn + tc * 4 + 1];
    o.z = acc[i][2] + bias[bn + tc * 4 + 2];
    o.w = acc[i][3] + bias[bn + tc * 4 + 3];
    *reinterpret_cast<float4*>(&C[(size_t)row * DM + bn + tc * 4]) = o;
  }
}

// ---------------- blocks 1-3 scores ----------------
__global__ __launch_bounds__(256) void dt_scores_nt(const float* __restrict__ Qp,
                                                    float* __restrict__ S) {
  const int bz = blockIdx.z;
  const int b = bz >> 3, h = bz & 7;
  const float* Q = Qp + (size_t)b * SEQL * DM + h * DKH;
  __shared__ float Qs[16][33], Ks[16][33];
  const int tid = threadIdx.x;
  const int tj = tid & 15, ti = tid >> 4;
  const int i0 = blockIdx.x * 16, j0 = blockIdx.y * 16;
  const int r = tid >> 5, c = tid & 31;
  Qs[r][c]     = Q[(size_t)(i0 + r) * DM + c];
  Qs[r + 8][c] = Q[(size_t)(i0 + 8 + r) * DM + c];
  Ks[r][c]     = Q[(size_t)(j0 + r) * DM + c];
  Ks[r + 8][c] = Q[(size_t)(j0 + 8 + r) * DM + c];
  __syncthreads();
  float acc = 0.f;
#pragma unroll
  for (int k = 0; k < DKH; ++k) acc = fmaf(Qs[ti][k], Ks[tj][k], acc);
  S[((size_t)bz * SEQL + i0 + ti) * SEQL + j0 + tj] = acc * 0.17677669529663687f;
}

// ---------------- block 4 base scores (i-independent) ----------------
__global__ __launch_bounds__(256) void dt_scores4(const float* __restrict__ Q4h,
                                                  const float* __restrict__ Kp,
                                                  float* __restrict__ S0) {
  const int idx = blockIdx.x * 256 + threadIdx.x;  // ((b*16+nk)*8+h)*256 + j
  const int j = idx & 255;
  const int h = (idx >> 8) & 7;
  const int nk = (idx >> 11) & 15;
  const int b = idx >> 15;
  const float* q = Q4h + nk * DM + h * DKH;
  const float* k = Kp + ((size_t)(b * SEQL + j)) * DM + h * DKH;
  float acc = 0.f;
#pragma unroll
  for (int c = 0; c < DKH; ++c) acc = fmaf(q[c], k[c], acc);
  S0[idx] = acc * 0.17677669529663687f;
}

// ---------------- block 4 prefix precompute: P_j = cumsum exp(s - rowmax) ----------------
// one wave per base row (b,nk,h): 512 rows
__global__ __launch_bounds__(256) void dt_prep4(const float* __restrict__ S0,
                                                float* __restrict__ Pfx) {
  const int wid = threadIdx.x >> 6, lane = threadIdx.x & 63;
  const int row = blockIdx.x * 4 + wid;  // [0,512)
  const float4 s4 = *reinterpret_cast<const float4*>(S0 + (size_t)row * SEQL + lane * 4);
  float s[4] = {s4.x, s4.y, s4.z, s4.w};
  float mx = fmaxf(fmaxf(s[0], s[1]), fmaxf(s[2], s[3]));
  mx = wave_red_max(mx);
  float e[4], t = 0.f;
#pragma unroll
  for (int q = 0; q < 4; ++q) { e[q] = __expf(s[q] - mx); t += e[q]; }
  const float incl = wave_incl_scan(t);
  float run = incl - t;
  float4 o;
  run += e[0]; o.x = run;
  run += e[1]; o.y = run;
  run += e[2]; o.z = run;
  run += e[3]; o.w = run;
  *reinterpret_cast<float4*>(Pfx + (size_t)row * SEQL + lane * 4) = o;
}

// ---------------- decay-softmax blocks 1-3, wave-per-row ----------------
// row = (b*8+h)*256 + i ; mask j<=i, no maxout
__global__ __launch_bounds__(256) void dt_softmax13w(const float* __restrict__ S,
                                                     float* __restrict__ P,
                                                     const float* __restrict__ gam) {
  const int wid = threadIdx.x >> 6, lane = threadIdx.x & 63;
  const int row = blockIdx.x * 4 + wid;
  const int i = row & 255, h = (row >> 8) & 7;
  const float g = -fabsf(gam[h]);
  const int jb = lane * 4;
  const float4 s4 = *reinterpret_cast<const float4*>(S + (size_t)row * SEQL + jb);
  float s[4] = {s4.x, s4.y, s4.z, s4.w};
  // first masked softmax
  float mx = -1e30f;
#pragma unroll
  for (int q = 0; q < 4; ++q) if (jb + q <= i) mx = fmaxf(mx, s[q]);
  mx = wave_red_max(mx);
  float e[4], t = 0.f;
#pragma unroll
  for (int q = 0; q < 4; ++q) { e[q] = (jb + q <= i) ? __expf(s[q] - mx) : 0.f; t += e[q]; }
  const float incl = wave_incl_scan(t);
  const float total = __shfl(incl, 63);
  const float inv = 1.f / total;
  float run = incl - t;
  float p2[4], t2 = 0.f;
#pragma unroll
  for (int q = 0; q < 4; ++q) {
    run += e[q];
    const float cum = run * inv;                    // inclusive cumsum of softmax
    float dd = (1.f - cum) * (float)(i - jb - q);   // disttotal = 1
    dd = dd > 0.f ? dd : 0.f;
    float eff = __expf(g * sqrtf(dd));
    eff = fmaxf(eff, 1e-5f);                        // upper clip 1e5 unreachable (eff<=1)
    const float y = s[q] * eff;
    p2[q] = (jb + q <= i) ? __expf(y) : 0.f;        // |y| small: no max-sub needed
    t2 += p2[q];
  }
  const float sum2 = wave_red_sum(t2);
  const float inv2 = 1.f / sum2;
  float4 o = {p2[0] * inv2, p2[1] * inv2, p2[2] * inv2, p2[3] * inv2};
  *reinterpret_cast<float4*>(P + (size_t)row * SEQL + jb) = o;
}

// ---------------- decay-softmax block 4, wave-per-row, prefix-factored ----------------
// row = ((b*16+nk)*8+h)*256 + i ; mask j<i, maxout; writes k_scores[b,h,i,nk,j]
__global__ __launch_bounds__(256) void dt_softmax4w(const float* __restrict__ S0,
                                                    const float* __restrict__ Pfx,
                                                    float* __restrict__ KS,
                                                    const float* __restrict__ gam) {
  const int wid = threadIdx.x >> 6, lane = threadIdx.x & 63;
  const int row = blockIdx.x * 4 + wid;
  const int i = row & 255;
  const int rb = row >> 8;             // (b*16+nk)*8+h
  const int h = rb & 7, nk = (rb >> 3) & 15, b = rb >> 7;
  const int jb = lane * 4;
  float* outp = KS + ((((size_t)(b * NH + h)) * SEQL + i) * NKN + nk) * SEQL + jb;
  if (i == 0) {                        // fully-masked row -> zeros (wave-uniform branch)
    float4 z = {0.f, 0.f, 0.f, 0.f};
    *reinterpret_cast<float4*>(outp) = z;
    return;
  }
  const float* srow = S0 + (size_t)rb * SEQL;
  const float* prow = Pfx + (size_t)rb * SEQL;
  const float4 s4 = *reinterpret_cast<const float4*>(srow + jb);
  const float4 p4 = *reinterpret_cast<const float4*>(prow + jb);
  const float s[4] = {s4.x, s4.y, s4.z, s4.w};
  const float pj[4] = {p4.x, p4.y, p4.z, p4.w};
  const float rinv = 1.f / prow[i - 1];     // broadcast scalar load
  const float g = -fabsf(gam[h]);
  float ey[4], t = 0.f, m = 0.f;
#pragma unroll
  for (int q = 0; q < 4; ++q) {
    const float cum = pj[q] * rinv;                 // P_j / P_{i-1}
    float dd = (1.f - cum) * (float)(i - jb - q);
    dd = dd > 0.f ? dd : 0.f;
    float eff = __expf(g * sqrtf(dd));
    eff = fmaxf(eff, 1e-5f);
    const float y = s[q] * eff;
    ey[q] = (jb + q < i) ? __expf(y) : 0.f;
    t += ey[q];
    m = fmaxf(m, ey[q]);
  }
#pragma unroll
  for (int o = 32; o > 0; o >>= 1) {
    t += __shfl_xor(t, o);
    m = fmaxf(m, __shfl_xor(m, o));
  }
  const float inv2 = 1.f / t;
  const float maxp = m * inv2;
  const float scale = fminf(1.f / (maxp + 1e-8f), 5.f);
  const float f = inv2 * scale;
  float4 o = {ey[0] * f, ey[1] * f, ey[2] * f, ey[3] * f};
  *reinterpret_cast<float4*>(outp) = o;
}

// ---------------- PV blocks 1-3 ----------------
__global__ __launch_bounds__(256) void dt_pv13(const float* __restrict__ P,
                                               const float* __restrict__ Vp,
                                               float* __restrict__ O) {
  __shared__ float Ps[32][33];
  __shared__ float Vs[32][33];
  const int bh = blockIdx.y, b = bh >> 3, h = bh & 7;
  const int i0 = blockIdx.x * 32;
  const int tid = threadIdx.x;
  const int c = tid & 31, ir = tid >> 5;
  float acc[4] = {0.f, 0.f, 0.f, 0.f};
  const float* Prow = P + ((size_t)bh * SEQL + i0) * SEQL;
  const float* Vbase = Vp + (size_t)b * SEQL * DM + h * DKH;
  for (int j0 = 0; j0 < SEQL; j0 += 32) {
#pragma unroll
    for (int k = 0; k < 4; ++k) {
      Ps[ir + k * 8][c] = Prow[(size_t)(ir + k * 8) * SEQL + j0 + c];
      Vs[ir + k * 8][c] = Vbase[(size_t)(j0 + ir + k * 8) * DM + c];
    }
    __syncthreads();
#pragma unroll
    for (int jj = 0; jj < 32; ++jj) {
      const float v = Vs[jj][c];
#pragma unroll
      for (int k = 0; k < 4; ++k) acc[k] = fmaf(Ps[ir + k * 8][jj], v, acc[k]);
    }
    __syncthreads();
  }
#pragma unroll
  for (int k = 0; k < 4; ++k)
    O[((size_t)(b * SEQL + i0 + ir + k * 8)) * DM + h * DKH + c] = acc[k];
}

// ---------------- PV block 4 ----------------
__global__ __launch_bounds__(256) void dt_pv4(const float* __restrict__ KS,
                                              const float* __restrict__ Vp,
                                              float* __restrict__ O) {
  __shared__ float Ps[32][33];
  __shared__ float Vs[32][33];
  const int z = blockIdx.y;  // (b*16+nk)*8+h
  const int h = z & 7, nk = (z >> 3) & 15, b = z >> 7;
  const int i0 = blockIdx.x * 32;
  const int tid = threadIdx.x;
  const int c = tid & 31, ir = tid >> 5;
  float acc[4] = {0.f, 0.f, 0.f, 0.f};
  const float* Pbase = KS + ((size_t)(b * NH + h)) * SEQL * NKN * SEQL + (size_t)nk * SEQL;
  const float* Vbase = Vp + (size_t)b * SEQL * DM + h * DKH;
  for (int j0 = 0; j0 < SEQL; j0 += 32) {
#pragma unroll
    for (int k = 0; k < 4; ++k) {
      const int i = i0 + ir + k * 8;
      Ps[ir + k * 8][c] = Pbase[(size_t)i * (NKN * SEQL) + j0 + c];
      Vs[ir + k * 8][c] = Vbase[(size_t)(j0 + ir + k * 8) * DM + c];
    }
    __syncthreads();
#pragma unroll
    for (int jj = 0; jj < 32; ++jj) {
      const float v = Vs[jj][c];
#pragma unroll
      for (int k = 0; k < 4; ++k) acc[k] = fmaf(Ps[ir + k * 8][jj], v, acc[k]);
    }
    __syncthreads();
  }
  const int bnk = (z >> 3);
#pragma unroll
  for (int k = 0; k < 4; ++k)
    O[((size_t)(bnk * SEQL + i0 + ir + k * 8)) * DM + h * DKH + c] = acc[k];
}

// ---------------- residual + LayerNorm blocks 1-3, wave-per-row ----------------
__global__ __launch_bounds__(256) void dt_ln_res_w(const float* __restrict__ X,
                                                   const float* __restrict__ Y,
                                                   const float* __restrict__ g,
                                                   const float* __restrict__ bb,
                                                   float* __restrict__ Z) {
  const int wid = threadIdx.x >> 6, lane = threadIdx.x & 63;
  const int row = blockIdx.x * 4 + wid;
  const int jb = lane * 4;
  const float4 x4 = *reinterpret_cast<const float4*>(X + (size_t)row * DM + jb);
  const float4 y4 = *reinterpret_cast<const float4*>(Y + (size_t)row * DM + jb);
  float x[4] = {x4.x + y4.x, x4.y + y4.y, x4.z + y4.z, x4.w + y4.w};
  const float mean = wave_red_sum(x[0] + x[1] + x[2] + x[3]) * (1.f / 256.f);
  float vs = 0.f;
#pragma unroll
  for (int q = 0; q < 4; ++q) { const float d = x[q] - mean; vs += d * d; }
  const float var = wave_red_sum(vs) * (1.f / 256.f);
  const float rstd = 1.f / sqrtf(var + 1e-5f);
  const float4 g4 = *reinterpret_cast<const float4*>(g + jb);
  const float4 b4 = *reinterpret_cast<const float4*>(bb + jb);
  float4 o;
  o.x = (x[0] - mean) * rstd * g4.x + b4.x;
  o.y = (x[1] - mean) * rstd * g4.y + b4.y;
  o.z = (x[2] - mean) * rstd * g4.z + b4.z;
  o.w = (x[3] - mean) * rstd * g4.w + b4.w;
  *reinterpret_cast<float4*>(Z + (size_t)row * DM + jb) = o;
}

// ---------------- residual + LayerNorm block 4 (residual = know, transposed z write) ----------------
__global__ __launch_bounds__(256) void dt_ln4w(const float* __restrict__ know,
                                               const float* __restrict__ Y,
                                               const float* __restrict__ g,
                                               const float* __restrict__ bb,
                                               float* __restrict__ Z) {
  const int wid = threadIdx.x >> 6, lane = threadIdx.x & 63;
  const int row = blockIdx.x * 4 + wid;  // (b*16+nk)*256 + i
  const int i = row & 255;
  const int nk = (row >> 8) & 15;
  const int b = row >> 12;
  const int jb = lane * 4;
  const float4 k4 = *reinterpret_cast<const float4*>(know + (size_t)nk * DM + jb);
  const float4 y4 = *reinterpret_cast<const float4*>(Y + (size_t)row * DM + jb);
  float x[4] = {k4.x + y4.x, k4.y + y4.y, k4.z + y4.z, k4.w + y4.w};
  const float mean = wave_red_sum(x[0] + x[1] + x[2] + x[3]) * (1.f / 256.f);
  float vs = 0.f;
#pragma unroll
  for (int q = 0; q < 4; ++q) { const float d = x[q] - mean; vs += d * d; }
  const float var = wave_red_sum(vs) * (1.f / 256.f);
  const float rstd = 1.f / sqrtf(var + 1e-5f);
  const float4 g4 = *reinterpret_cast<const float4*>(g + jb);
  const float4 b4 = *reinterpret_cast<const float4*>(bb + jb);
  float4 o;
  o.x = (x[0] - mean) * rstd * g4.x + b4.x;
  o.y = (x[1] - mean) * rstd * g4.y + b4.y;
  o.z = (x[2] - mean) * rstd * g4.z + b4.z;
  o.w = (x[3] - mean) * rstd * g4.w + b4.w;
  *reinterpret_cast<float4*>(Z + ((size_t)(b * SEQL + i)) * (NKN * DM) + (size_t)nk * DM + jb) = o;
}

// ---------------- launcher ----------------
extern "C" void kernel_launch(void* const* d_in, const int* in_sizes, int n_in,
                              void* d_out, int out_size, void* d_ws, size_t ws_size,
                              hipStream_t stream) {
  (void)in_sizes; (void)n_in; (void)out_size; (void)ws_size;
  const float* q_emb = (const float*)d_in[0];
  const float* s_emb = (const float*)d_in[1];
  const float* know  = (const float*)d_in[3];
  const float* Wq1 = (const float*)d_in[4],  *bq1 = (const float*)d_in[5];
  const float* Wv1 = (const float*)d_in[6],  *bv1 = (const float*)d_in[7];
  const float* Wo1 = (const float*)d_in[8],  *bo1 = (const float*)d_in[9];
  const float* gam1 = (const float*)d_in[10], *lng1 = (const float*)d_in[11], *lnb1 = (const float*)d_in[12];
  const float* Wq2 = (const float*)d_in[13], *bq2 = (const float*)d_in[14];
  const float* Wv2 = (const float*)d_in[15], *bv2 = (const float*)d_in[16];
  const float* Wo2 = (const float*)d_in[17], *bo2 = (const float*)d_in[18];
  const float* gam2 = (const float*)d_in[19], *lng2 = (const float*)d_in[20], *lnb2 = (const float*)d_in[21];
  const float* Wq3 = (const float*)d_in[22], *bq3 = (const float*)d_in[23];
  const float* Wv3 = (const float*)d_in[24], *bv3 = (const float*)d_in[25];
  const float* Wo3 = (const float*)d_in[26], *bo3 = (const float*)d_in[27];
  const float* gam3 = (const float*)d_in[28], *lng3 = (const float*)d_in[29], *lnb3 = (const float*)d_in[30];
  const float* Wq4 = (const float*)d_in[31], *bq4 = (const float*)d_in[32];
  const float* Wk4 = (const float*)d_in[33], *bk4 = (const float*)d_in[34];
  const float* Wv4 = (const float*)d_in[35], *bv4 = (const float*)d_in[36];
  const float* Wo4 = (const float*)d_in[37], *bo4 = (const float*)d_in[38];
  const float* gam4 = (const float*)d_in[39], *lng4 = (const float*)d_in[40], *lnb4 = (const float*)d_in[41];

  float* ws = (float*)d_ws;
  float* Qp  = ws;                   // 262144  (also Kp4)
  float* Vp  = Qp + 262144;          // 262144  (also Vp4)
  float* S   = Vp + 262144;          // 2097152
  float* O   = S + 2097152;          // 262144  (block-4: reused as Pfx)
  float* OW  = O + 262144;           // 262144
  float* hq  = OW + 262144;          // 262144
  float* hs  = hq + 262144;          // 262144
  float* pbf = hs + 262144;          // 262144
  float* Q4h = pbf + 262144;         // 4096
  float* S0  = Q4h + 4096;           // 131072
  float* OW4 = S0 + 131072;          // 4194304

  float* zout = (float*)d_out;
  float* qsc  = zout + 4194304;
  float* ksc  = qsc + 2097152;
  float* O4   = zout;                // scratch; ln4w fully rewrites zout at the end
  float* Pfx  = O;                   // O is dead by block 4

  const dim3 thr(256);

  // ---- block 1 (q_emb -> hq) ----
  dt_gemm_bias<<<dim3(16, 4), thr, 0, stream>>>(q_emb, Wq1, bq1, Qp, 1024);
  dt_gemm_bias<<<dim3(16, 4), thr, 0, stream>>>(q_emb, Wv1, bv1, Vp, 1024);
  dt_scores_nt<<<dim3(16, 16, 32), thr, 0, stream>>>(Qp, S);
  dt_softmax13w<<<dim3(2048), thr, 0, stream>>>(S, S, gam1);
  dt_pv13<<<dim3(8, 32), thr, 0, stream>>>(S, Vp, O);
  dt_gemm_bias<<<dim3(16, 4), thr, 0, stream>>>(O, Wo1, bo1, OW, 1024);
  dt_ln_res_w<<<dim3(256), thr, 0, stream>>>(q_emb, OW, lng1, lnb1, hq);

  // ---- block 2 (s_emb -> hs) ----
  dt_gemm_bias<<<dim3(16, 4), thr, 0, stream>>>(s_emb, Wq2, bq2, Qp, 1024);
  dt_gemm_bias<<<dim3(16, 4), thr, 0, stream>>>(s_emb, Wv2, bv2, Vp, 1024);
  dt_scores_nt<<<dim3(16, 16, 32), thr, 0, stream>>>(Qp, S);
  dt_softmax13w<<<dim3(2048), thr, 0, stream>>>(S, S, gam2);
  dt_pv13<<<dim3(8, 32), thr, 0, stream>>>(S, Vp, O);
  dt_gemm_bias<<<dim3(16, 4), thr, 0, stream>>>(O, Wo2, bo2, OW, 1024);
  dt_ln_res_w<<<dim3(256), thr, 0, stream>>>(s_emb, OW, lng2, lnb2, hs);

  // ---- block 3 (q=k=hq, v=hs -> pbf; scores -> q_scores out) ----
  dt_gemm_bias<<<dim3(16, 4), thr, 0, stream>>>(hq, Wq3, bq3, Qp, 1024);
  dt_gemm_bias<<<dim3(16, 4), thr, 0, stream>>>(hs, Wv3, bv3, Vp, 1024);
  dt_scores_nt<<<dim3(16, 16, 32), thr, 0, stream>>>(Qp, S);
  dt_softmax13w<<<dim3(2048), thr, 0, stream>>>(S, qsc, gam3);
  dt_pv13<<<dim3(8, 32), thr, 0, stream>>>(qsc, Vp, O);
  dt_gemm_bias<<<dim3(16, 4), thr, 0, stream>>>(O, Wo3, bo3, OW, 1024);
  dt_ln_res_w<<<dim3(256), thr, 0, stream>>>(hq, OW, lng3, lnb3, pbf);

  // ---- block 4 (query = know broadcast; k from hq; v from pbf) ----
  dt_gemm_bias<<<dim3(1, 4),  thr, 0, stream>>>(know, Wq4, bq4, Q4h, 16);
  dt_gemm_bias<<<dim3(16, 4), thr, 0, stream>>>(hq,  Wk4, bk4, Qp, 1024);   // Kp4
  dt_gemm_bias<<<dim3(16, 4), thr, 0, stream>>>(pbf, Wv4, bv4, Vp, 1024);   // Vp4
  dt_scores4<<<dim3(512), thr, 0, stream>>>(Q4h, Qp, S0);
  dt_prep4<<<dim3(128), thr, 0, stream>>>(S0, Pfx);
  dt_softmax4w<<<dim3(32768), thr, 0, stream>>>(S0, Pfx, ksc, gam4);
  dt_pv4<<<dim3(8, 512), thr, 0, stream>>>(ksc, Vp, O4);
  dt_gemm_bias<<<dim3(256, 4), thr, 0, stream>>>(O4, Wo4, bo4, OW4, 16384);
  dt_ln4w<<<dim3(4096), thr, 0, stream>>>(know, OW4, lng4, lnb4, zout);
}

// Round 4
// 529.979 us; speedup vs baseline: 1.8094x; 1.3590x over previous
//
#include <hip/hip_runtime.h>
#include <math.h>

#define SEQL 256
#define DM   256
#define NH   8
#define DKH  32
#define BSZ  4
#define NKN  16

// ---------------- wave (64-lane) helpers ----------------
__device__ __forceinline__ float wave_red_sum(float v) {
#pragma unroll
  for (int o = 32; o > 0; o >>= 1) v += __shfl_xor(v, o);
  return v;
}
__device__ __forceinline__ float wave_red_max(float v) {
#pragma unroll
  for (int o = 32; o > 0; o >>= 1) v = fmaxf(v, __shfl_xor(v, o));
  return v;
}
__device__ __forceinline__ float wave_incl_scan(float v) {
  const int lane = threadIdx.x & 63;
#pragma unroll
  for (int o = 1; o < 64; o <<= 1) {
    float u = __shfl_up(v, o);
    if (lane >= o) v += u;
  }
  return v;
}

// ---------------- multi-set GEMM: C[M,256] = A[M,256] @ W[256,256] + bias ----------------
struct GemmSet { const float* A; const float* W; const float* bias; float* C; int M; };
struct Gemm4 { GemmSet s[4]; };

__global__ __launch_bounds__(256) void dt_gemmN(Gemm4 args) {
  const GemmSet g = args.s[blockIdx.z];
  const int bm = blockIdx.x * 64, bn = blockIdx.y * 64;
  if (bm >= g.M) return;
  __shared__ float As[16][68];
  __shared__ float Bs[16][68];
  const int tid = threadIdx.x;
  const int tc = tid & 15, tr = tid >> 4;
  float acc[4][4] = {};
  for (int k0 = 0; k0 < DM; k0 += 16) {
    {
      const int m = tid >> 2, kq = tid & 3;
      int row = bm + m; row = row < g.M ? row : (g.M - 1);
      const float4 v = *reinterpret_cast<const float4*>(&g.A[(size_t)row * DM + k0 + kq * 4]);
      As[kq * 4 + 0][m] = v.x; As[kq * 4 + 1][m] = v.y;
      As[kq * 4 + 2][m] = v.z; As[kq * 4 + 3][m] = v.w;
    }
    {
      const int k = tid >> 4, nq = tid & 15;
      const float4 v = *reinterpret_cast<const float4*>(&g.W[(size_t)(k0 + k) * DM + bn + nq * 4]);
      *reinterpret_cast<float4*>(&Bs[k][nq * 4]) = v;
    }
    __syncthreads();
#pragma unroll
    for (int k = 0; k < 16; ++k) {
      float a[4], b[4];
#pragma unroll
      for (int i = 0; i < 4; ++i) a[i] = As[k][tr * 4 + i];
#pragma unroll
      for (int j = 0; j < 4; ++j) b[j] = Bs[k][tc * 4 + j];
#pragma unroll
      for (int i = 0; i < 4; ++i)
#pragma unroll
        for (int j = 0; j < 4; ++j) acc[i][j] = fmaf(a[i], b[j], acc[i][j]);
    }
    __syncthreads();
  }
#pragma unroll
  for (int i = 0; i < 4; ++i) {
    const int row = bm + tr * 4 + i;
    if (row >= g.M) continue;
    float4 o;
    o.x = acc[i][0] + g.bias[bn + tc * 4 + 0];
    o.y = acc[i][1] + g.bias[bn + tc * 4 + 1];
    o.z = acc[i][2] + g.bias[bn + tc * 4 + 2];
    o.w = acc[i][3] + g.bias[bn + tc * 4 + 3];
    *reinterpret_cast<float4*>(&g.C[(size_t)row * DM + bn + tc * 4]) = o;
  }
}

// ---------------- blocks 1-3 scores (2-set) ----------------
__global__ __launch_bounds__(256) void dt_scores_nt2(const float* __restrict__ Q0,
                                                     const float* __restrict__ Q1,
                                                     float* __restrict__ Sa,
                                                     float* __restrict__ Sb) {
  const int z = blockIdx.z;
  const int set = z >> 5, bh = z & 31;
  const float* Qp = set ? Q1 : Q0;
  float* S = set ? Sb : Sa;
  const int b = bh >> 3, h = bh & 7;
  const float* Q = Qp + (size_t)b * SEQL * DM + h * DKH;
  __shared__ float Qs[16][33], Ks[16][33];
  const int tid = threadIdx.x;
  const int tj = tid & 15, ti = tid >> 4;
  const int i0 = blockIdx.x * 16, j0 = blockIdx.y * 16;
  const int r = tid >> 5, c = tid & 31;
  Qs[r][c]     = Q[(size_t)(i0 + r) * DM + c];
  Qs[r + 8][c] = Q[(size_t)(i0 + 8 + r) * DM + c];
  Ks[r][c]     = Q[(size_t)(j0 + r) * DM + c];
  Ks[r + 8][c] = Q[(size_t)(j0 + 8 + r) * DM + c];
  __syncthreads();
  float acc = 0.f;
#pragma unroll
  for (int k = 0; k < DKH; ++k) acc = fmaf(Qs[ti][k], Ks[tj][k], acc);
  S[((size_t)bh * SEQL + i0 + ti) * SEQL + j0 + tj] = acc * 0.17677669529663687f;
}

// ---------------- block 4 base scores (i-independent) ----------------
__global__ __launch_bounds__(256) void dt_scores4(const float* __restrict__ Q4h,
                                                  const float* __restrict__ Kp,
                                                  float* __restrict__ S0) {
  const int idx = blockIdx.x * 256 + threadIdx.x;  // ((b*16+nk)*8+h)*256 + j
  const int j = idx & 255;
  const int h = (idx >> 8) & 7;
  const int nk = (idx >> 11) & 15;
  const int b = idx >> 15;
  const float* q = Q4h + nk * DM + h * DKH;
  const float* k = Kp + ((size_t)(b * SEQL + j)) * DM + h * DKH;
  float acc = 0.f;
#pragma unroll
  for (int c = 0; c < DKH; ++c) acc = fmaf(q[c], k[c], acc);
  S0[idx] = acc * 0.17677669529663687f;
}

// ---------------- block 4 prefix precompute ----------------
__global__ __launch_bounds__(256) void dt_prep4(const float* __restrict__ S0,
                                                float* __restrict__ Pfx) {
  const int wid = threadIdx.x >> 6, lane = threadIdx.x & 63;
  const int row = blockIdx.x * 4 + wid;
  const float4 s4 = *reinterpret_cast<const float4*>(S0 + (size_t)row * SEQL + lane * 4);
  float s[4] = {s4.x, s4.y, s4.z, s4.w};
  float mx = fmaxf(fmaxf(s[0], s[1]), fmaxf(s[2], s[3]));
  mx = wave_red_max(mx);
  float e[4], t = 0.f;
#pragma unroll
  for (int q = 0; q < 4; ++q) { e[q] = __expf(s[q] - mx); t += e[q]; }
  const float incl = wave_incl_scan(t);
  float run = incl - t;
  float4 o;
  run += e[0]; o.x = run;
  run += e[1]; o.y = run;
  run += e[2]; o.z = run;
  run += e[3]; o.w = run;
  *reinterpret_cast<float4*>(Pfx + (size_t)row * SEQL + lane * 4) = o;
}

// ---------------- decay-softmax blocks 1-3 (2-set), wave-per-row ----------------
__global__ __launch_bounds__(256) void dt_softmax13w2(const float* __restrict__ Sa,
                                                      const float* __restrict__ Sb,
                                                      float* __restrict__ Pa,
                                                      float* __restrict__ Pb,
                                                      const float* __restrict__ g0,
                                                      const float* __restrict__ g1) {
  const int wid = threadIdx.x >> 6, lane = threadIdx.x & 63;
  const int grow = blockIdx.x * 4 + wid;
  const int set = grow >> 13;
  const int row = grow & 8191;
  const float* S = set ? Sb : Sa;
  float* P = set ? Pb : Pa;
  const float* gam = set ? g1 : g0;
  const int i = row & 255, h = (row >> 8) & 7;
  const float g = -fabsf(gam[h]);
  const int jb = lane * 4;
  const float4 s4 = *reinterpret_cast<const float4*>(S + (size_t)row * SEQL + jb);
  float s[4] = {s4.x, s4.y, s4.z, s4.w};
  float mx = -1e30f;
#pragma unroll
  for (int q = 0; q < 4; ++q) if (jb + q <= i) mx = fmaxf(mx, s[q]);
  mx = wave_red_max(mx);
  float e[4], t = 0.f;
#pragma unroll
  for (int q = 0; q < 4; ++q) { e[q] = (jb + q <= i) ? __expf(s[q] - mx) : 0.f; t += e[q]; }
  const float incl = wave_incl_scan(t);
  const float total = __shfl(incl, 63);
  const float inv = 1.f / total;
  float run = incl - t;
  float p2[4], t2 = 0.f;
#pragma unroll
  for (int q = 0; q < 4; ++q) {
    run += e[q];
    const float cum = run * inv;
    float dd = (1.f - cum) * (float)(i - jb - q);
    dd = dd > 0.f ? dd : 0.f;
    float eff = __expf(g * sqrtf(dd));
    eff = fmaxf(eff, 1e-5f);
    const float y = s[q] * eff;
    p2[q] = (jb + q <= i) ? __expf(y) : 0.f;
    t2 += p2[q];
  }
  const float sum2 = wave_red_sum(t2);
  const float inv2 = 1.f / sum2;
  float4 o = {p2[0] * inv2, p2[1] * inv2, p2[2] * inv2, p2[3] * inv2};
  *reinterpret_cast<float4*>(P + (size_t)row * SEQL + jb) = o;
}

// ---------------- fused decay-softmax + PV, block 4 ----------------
// one block per (b,nk,h): writes k_scores[b,h,:,nk,:] and O4[(b*16+nk)*256+i, h*32+c]
__global__ __launch_bounds__(256) void dt_sm_pv4(const float* __restrict__ S0,
                                                 const float* __restrict__ Pfx,
                                                 const float* __restrict__ Vp,
                                                 const float* __restrict__ gam,
                                                 float* __restrict__ KS,
                                                 float* __restrict__ O) {
  __shared__ float Vs[256][32];   // V slice, [j][c]
  __shared__ float Pl[32][260];   // P rows for one 32-i chunk (+4 pad: conflict-free)
  __shared__ float Pfl[256];      // prefix row
  const int z = blockIdx.x;       // (b*16+nk)*8+h
  const int h = z & 7, b = z >> 7;
  const int nk = (z >> 3) & 15, bnk = z >> 3;
  const int tid = threadIdx.x, lane = tid & 63, w = tid >> 6;
  const float* Vbase = Vp + (size_t)b * SEQL * DM + h * DKH;
  {
    const int j = tid >> 3, c4 = (tid & 7) * 4;
    for (int jj = 0; jj < 256; jj += 32) {
      const float4 v = *reinterpret_cast<const float4*>(Vbase + (size_t)(jj + j) * DM + c4);
      *reinterpret_cast<float4*>(&Vs[jj + j][c4]) = v;
    }
  }
  if (tid < 64) {
    const float4 p = *reinterpret_cast<const float4*>(Pfx + (size_t)z * SEQL + tid * 4);
    *reinterpret_cast<float4*>(&Pfl[tid * 4]) = p;
  }
  const float4 s4 = *reinterpret_cast<const float4*>(S0 + (size_t)z * SEQL + lane * 4);
  const float4 p4 = *reinterpret_cast<const float4*>(Pfx + (size_t)z * SEQL + lane * 4);
  const float s[4] = {s4.x, s4.y, s4.z, s4.w};
  const float pj[4] = {p4.x, p4.y, p4.z, p4.w};
  const float g = -fabsf(gam[h]);
  const int jb = lane * 4;
  __syncthreads();

  for (int chunk = 0; chunk < 8; ++chunk) {
    const int i0 = chunk * 32;
#pragma unroll
    for (int r = 0; r < 8; ++r) {
      const int il = w * 8 + r;
      const int i = i0 + il;
      float pv[4];
      if (i == 0) {
        pv[0] = pv[1] = pv[2] = pv[3] = 0.f;
      } else {
        const float rinv = 1.f / Pfl[i - 1];
        float t = 0.f, m = 0.f;
#pragma unroll
        for (int q = 0; q < 4; ++q) {
          const float cum = pj[q] * rinv;
          float dd = (1.f - cum) * (float)(i - jb - q);
          dd = dd > 0.f ? dd : 0.f;
          float eff = __expf(g * sqrtf(dd));
          eff = fmaxf(eff, 1e-5f);
          const float y = s[q] * eff;
          pv[q] = (jb + q < i) ? __expf(y) : 0.f;
          t += pv[q];
          m = fmaxf(m, pv[q]);
        }
#pragma unroll
        for (int o = 32; o > 0; o >>= 1) {
          t += __shfl_xor(t, o);
          m = fmaxf(m, __shfl_xor(m, o));
        }
        const float inv2 = 1.f / t;
        const float scale = fminf(1.f / (m * inv2 + 1e-8f), 5.f);
        const float f = inv2 * scale;
        pv[0] *= f; pv[1] *= f; pv[2] *= f; pv[3] *= f;
      }
      const float4 o4 = {pv[0], pv[1], pv[2], pv[3]};
      *reinterpret_cast<float4*>(KS + ((((size_t)(b * NH + h)) * SEQL + i) * NKN + nk) * SEQL + jb) = o4;
      *reinterpret_cast<float4*>(&Pl[il][jb]) = o4;
    }
    __syncthreads();
    // PV for the 32 rows: thread (il = tid>>3, cg = tid&7) -> 1 i, 4 c
    const int il = tid >> 3, cg = tid & 7;
    float ax = 0.f, ay = 0.f, az = 0.f, aw = 0.f;
#pragma unroll 8
    for (int j4 = 0; j4 < 64; ++j4) {
      const float4 pp = *reinterpret_cast<const float4*>(&Pl[il][j4 * 4]);
      const float4 v0 = *reinterpret_cast<const float4*>(&Vs[j4 * 4 + 0][cg * 4]);
      const float4 v1 = *reinterpret_cast<const float4*>(&Vs[j4 * 4 + 1][cg * 4]);
      const float4 v2 = *reinterpret_cast<const float4*>(&Vs[j4 * 4 + 2][cg * 4]);
      const float4 v3 = *reinterpret_cast<const float4*>(&Vs[j4 * 4 + 3][cg * 4]);
      ax = fmaf(pp.x, v0.x, ax); ax = fmaf(pp.y, v1.x, ax); ax = fmaf(pp.z, v2.x, ax); ax = fmaf(pp.w, v3.x, ax);
      ay = fmaf(pp.x, v0.y, ay); ay = fmaf(pp.y, v1.y, ay); ay = fmaf(pp.z, v2.y, ay); ay = fmaf(pp.w, v3.y, ay);
      az = fmaf(pp.x, v0.z, az); az = fmaf(pp.y, v1.z, az); az = fmaf(pp.z, v2.z, az); az = fmaf(pp.w, v3.z, az);
      aw = fmaf(pp.x, v0.w, aw); aw = fmaf(pp.y, v1.w, aw); aw = fmaf(pp.z, v2.w, aw); aw = fmaf(pp.w, v3.w, aw);
    }
    const float4 oo = {ax, ay, az, aw};
    *reinterpret_cast<float4*>(O + ((size_t)(bnk * SEQL + i0 + il)) * DM + h * DKH + cg * 4) = oo;
    __syncthreads();  // Pl reused next chunk
  }
}

// ---------------- PV blocks 1-3 (2-set) ----------------
__global__ __launch_bounds__(256) void dt_pv13_2(const float* __restrict__ Pa,
                                                 const float* __restrict__ Pb,
                                                 const float* __restrict__ V0,
                                                 const float* __restrict__ V1,
                                                 float* __restrict__ Oa,
                                                 float* __restrict__ Ob) {
  __shared__ float Ps[32][33];
  __shared__ float Vs[32][33];
  const int z = blockIdx.y;
  const int set = z >> 5, bh = z & 31;
  const float* P = set ? Pb : Pa;
  const float* Vp = set ? V1 : V0;
  float* O = set ? Ob : Oa;
  const int b = bh >> 3, h = bh & 7;
  const int i0 = blockIdx.x * 32;
  const int tid = threadIdx.x;
  const int c = tid & 31, ir = tid >> 5;
  float acc[4] = {0.f, 0.f, 0.f, 0.f};
  const float* Prow = P + ((size_t)bh * SEQL + i0) * SEQL;
  const float* Vbase = Vp + (size_t)b * SEQL * DM + h * DKH;
  for (int j0 = 0; j0 < SEQL; j0 += 32) {
#pragma unroll
    for (int k = 0; k < 4; ++k) {
      Ps[ir + k * 8][c] = Prow[(size_t)(ir + k * 8) * SEQL + j0 + c];
      Vs[ir + k * 8][c] = Vbase[(size_t)(j0 + ir + k * 8) * DM + c];
    }
    __syncthreads();
#pragma unroll
    for (int jj = 0; jj < 32; ++jj) {
      const float v = Vs[jj][c];
#pragma unroll
      for (int k = 0; k < 4; ++k) acc[k] = fmaf(Ps[ir + k * 8][jj], v, acc[k]);
    }
    __syncthreads();
  }
#pragma unroll
  for (int k = 0; k < 4; ++k)
    O[((size_t)(b * SEQL + i0 + ir + k * 8)) * DM + h * DKH + c] = acc[k];
}

// ---------------- residual + LayerNorm (2-set), wave-per-row ----------------
__global__ __launch_bounds__(256) void dt_ln_res2(const float* __restrict__ X0,
                                                  const float* __restrict__ X1,
                                                  const float* __restrict__ Y0,
                                                  const float* __restrict__ Y1,
                                                  const float* __restrict__ G0,
                                                  const float* __restrict__ G1,
                                                  const float* __restrict__ B0,
                                                  const float* __restrict__ B1,
                                                  float* __restrict__ Z0,
                                                  float* __restrict__ Z1) {
  const int wid = threadIdx.x >> 6, lane = threadIdx.x & 63;
  const int grow = blockIdx.x * 4 + wid;
  const int set = grow >> 10;
  const int row = grow & 1023;
  const float* X = set ? X1 : X0;
  const float* Y = set ? Y1 : Y0;
  const float* g = set ? G1 : G0;
  const float* bb = set ? B1 : B0;
  float* Z = set ? Z1 : Z0;
  const int jb = lane * 4;
  const float4 x4 = *reinterpret_cast<const float4*>(X + (size_t)row * DM + jb);
  const float4 y4 = *reinterpret_cast<const float4*>(Y + (size_t)row * DM + jb);
  float x[4] = {x4.x + y4.x, x4.y + y4.y, x4.z + y4.z, x4.w + y4.w};
  const float mean = wave_red_sum(x[0] + x[1] + x[2] + x[3]) * (1.f / 256.f);
  float vs = 0.f;
#pragma unroll
  for (int q = 0; q < 4; ++q) { const float d = x[q] - mean; vs += d * d; }
  const float var = wave_red_sum(vs) * (1.f / 256.f);
  const float rstd = 1.f / sqrtf(var + 1e-5f);
  const float4 g4 = *reinterpret_cast<const float4*>(g + jb);
  const float4 b4 = *reinterpret_cast<const float4*>(bb + jb);
  float4 o;
  o.x = (x[0] - mean) * rstd * g4.x + b4.x;
  o.y = (x[1] - mean) * rstd * g4.y + b4.y;
  o.z = (x[2] - mean) * rstd * g4.z + b4.z;
  o.w = (x[3] - mean) * rstd * g4.w + b4.w;
  *reinterpret_cast<float4*>(Z + (size_t)row * DM + jb) = o;
}

// ---------------- residual + LayerNorm block 4 ----------------
__global__ __launch_bounds__(256) void dt_ln4w(const float* __restrict__ know,
                                               const float* __restrict__ Y,
                                               const float* __restrict__ g,
                                               const float* __restrict__ bb,
                                               float* __restrict__ Z) {
  const int wid = threadIdx.x >> 6, lane = threadIdx.x & 63;
  const int row = blockIdx.x * 4 + wid;  // (b*16+nk)*256 + i
  const int i = row & 255;
  const int nk = (row >> 8) & 15;
  const int b = row >> 12;
  const int jb = lane * 4;
  const float4 k4 = *reinterpret_cast<const float4*>(know + (size_t)nk * DM + jb);
  const float4 y4 = *reinterpret_cast<const float4*>(Y + (size_t)row * DM + jb);
  float x[4] = {k4.x + y4.x, k4.y + y4.y, k4.z + y4.z, k4.w + y4.w};
  const float mean = wave_red_sum(x[0] + x[1] + x[2] + x[3]) * (1.f / 256.f);
  float vs = 0.f;
#pragma unroll
  for (int q = 0; q < 4; ++q) { const float d = x[q] - mean; vs += d * d; }
  const float var = wave_red_sum(vs) * (1.f / 256.f);
  const float rstd = 1.f / sqrtf(var + 1e-5f);
  const float4 g4 = *reinterpret_cast<const float4*>(g + jb);
  const float4 b4 = *reinterpret_cast<const float4*>(bb + jb);
  float4 o;
  o.x = (x[0] - mean) * rstd * g4.x + b4.x;
  o.y = (x[1] - mean) * rstd * g4.y + b4.y;
  o.z = (x[2] - mean) * rstd * g4.z + b4.z;
  o.w = (x[3] - mean) * rstd * g4.w + b4.w;
  *reinterpret_cast<float4*>(Z + ((size_t)(b * SEQL + i)) * (NKN * DM) + (size_t)nk * DM + jb) = o;
}

// ---------------- launcher ----------------
extern "C" void kernel_launch(void* const* d_in, const int* in_sizes, int n_in,
                              void* d_out, int out_size, void* d_ws, size_t ws_size,
                              hipStream_t stream) {
  (void)in_sizes; (void)n_in; (void)out_size; (void)ws_size;
  const float* q_emb = (const float*)d_in[0];
  const float* s_emb = (const float*)d_in[1];
  const float* know  = (const float*)d_in[3];
  const float* Wq1 = (const float*)d_in[4],  *bq1 = (const float*)d_in[5];
  const float* Wv1 = (const float*)d_in[6],  *bv1 = (const float*)d_in[7];
  const float* Wo1 = (const float*)d_in[8],  *bo1 = (const float*)d_in[9];
  const float* gam1 = (const float*)d_in[10], *lng1 = (const float*)d_in[11], *lnb1 = (const float*)d_in[12];
  const float* Wq2 = (const float*)d_in[13], *bq2 = (const float*)d_in[14];
  const float* Wv2 = (const float*)d_in[15], *bv2 = (const float*)d_in[16];
  const float* Wo2 = (const float*)d_in[17], *bo2 = (const float*)d_in[18];
  const float* gam2 = (const float*)d_in[19], *lng2 = (const float*)d_in[20], *lnb2 = (const float*)d_in[21];
  const float* Wq3 = (const float*)d_in[22], *bq3 = (const float*)d_in[23];
  const float* Wv3 = (const float*)d_in[24], *bv3 = (const float*)d_in[25];
  const float* Wo3 = (const float*)d_in[26], *bo3 = (const float*)d_in[27];
  const float* gam3 = (const float*)d_in[28], *lng3 = (const float*)d_in[29], *lnb3 = (const float*)d_in[30];
  const float* Wq4 = (const float*)d_in[31], *bq4 = (const float*)d_in[32];
  const float* Wk4 = (const float*)d_in[33], *bk4 = (const float*)d_in[34];
  const float* Wv4 = (const float*)d_in[35], *bv4 = (const float*)d_in[36];
  const float* Wo4 = (const float*)d_in[37], *bo4 = (const float*)d_in[38];
  const float* gam4 = (const float*)d_in[39], *lng4 = (const float*)d_in[40], *lnb4 = (const float*)d_in[41];

  // workspace: 28 units of 262144 floats (28 MB)
  float* ws = (float*)d_ws;
  const size_t U = 262144;
  float* Qp0 = ws + 0 * U;           // also Qp3, Kp4
  float* Qp1 = ws + 1 * U;
  float* Vp0 = ws + 2 * U;           // also Vp3, Vp4
  float* Vp1 = ws + 3 * U;
  float* Sa  = ws + 4 * U;           // 8U (b12 set0, b3); b4: start of OW4 (16U)
  float* Sb  = ws + 12 * U;          // 8U
  float* O0  = ws + 20 * U;          // also O3, then Pfx (b4)
  float* O1  = ws + 21 * U;
  float* OW0 = ws + 22 * U;          // also OW3
  float* OW1 = ws + 23 * U;
  float* hq  = ws + 24 * U;
  float* hs  = ws + 25 * U;
  float* pbf = ws + 26 * U;
  float* Q4h = ws + 27 * U;          // 4096
  float* S0s = Q4h + 4096;           // 131072
  float* OW4 = Sa;                   // 16U (Sa..Sb dead in block 4)
  float* Pfx = O0;                   // dead after block-3 out-proj

  float* zout = (float*)d_out;
  float* qsc  = zout + 4194304;
  float* ksc  = qsc + 2097152;
  float* O4   = zout;                // scratch; ln4w fully rewrites zout at the end

  const dim3 thr(256);

  // ---- blocks 1+2 batched ----
  {
    Gemm4 a = {{{q_emb, Wq1, bq1, Qp0, 1024}, {q_emb, Wv1, bv1, Vp0, 1024},
                {s_emb, Wq2, bq2, Qp1, 1024}, {s_emb, Wv2, bv2, Vp1, 1024}}};
    dt_gemmN<<<dim3(16, 4, 4), thr, 0, stream>>>(a);
  }
  dt_scores_nt2<<<dim3(16, 16, 64), thr, 0, stream>>>(Qp0, Qp1, Sa, Sb);
  dt_softmax13w2<<<dim3(4096), thr, 0, stream>>>(Sa, Sb, Sa, Sb, gam1, gam2);
  dt_pv13_2<<<dim3(8, 64), thr, 0, stream>>>(Sa, Sb, Vp0, Vp1, O0, O1);
  {
    Gemm4 a = {{{O0, Wo1, bo1, OW0, 1024}, {O1, Wo2, bo2, OW1, 1024},
                {O0, Wo1, bo1, OW0, 1024}, {O1, Wo2, bo2, OW1, 1024}}};
    dt_gemmN<<<dim3(16, 4, 2), thr, 0, stream>>>(a);
  }
  dt_ln_res2<<<dim3(512), thr, 0, stream>>>(q_emb, s_emb, OW0, OW1, lng1, lng2, lnb1, lnb2, hq, hs);

  // ---- block 3 (q=k=hq, v=hs -> pbf; scores -> q_scores out) ----
  {
    Gemm4 a = {{{hq, Wq3, bq3, Qp0, 1024}, {hs, Wv3, bv3, Vp0, 1024},
                {hq, Wq3, bq3, Qp0, 1024}, {hs, Wv3, bv3, Vp0, 1024}}};
    dt_gemmN<<<dim3(16, 4, 2), thr, 0, stream>>>(a);
  }
  dt_scores_nt2<<<dim3(16, 16, 32), thr, 0, stream>>>(Qp0, Qp0, Sa, Sa);
  dt_softmax13w2<<<dim3(2048), thr, 0, stream>>>(Sa, Sa, qsc, qsc, gam3, gam3);
  dt_pv13_2<<<dim3(8, 32), thr, 0, stream>>>(qsc, qsc, Vp0, Vp0, O0, O0);
  {
    Gemm4 a = {{{O0, Wo3, bo3, OW0, 1024}, {O0, Wo3, bo3, OW0, 1024},
                {O0, Wo3, bo3, OW0, 1024}, {O0, Wo3, bo3, OW0, 1024}}};
    dt_gemmN<<<dim3(16, 4, 1), thr, 0, stream>>>(a);
  }
  dt_ln_res2<<<dim3(256), thr, 0, stream>>>(hq, hq, OW0, OW0, lng3, lng3, lnb3, lnb3, pbf, pbf);

  // ---- block 4 ----
  {
    Gemm4 a = {{{hq, Wk4, bk4, Qp0, 1024}, {pbf, Wv4, bv4, Vp0, 1024},
                {know, Wq4, bq4, Q4h, 16}, {know, Wq4, bq4, Q4h, 16}}};
    dt_gemmN<<<dim3(16, 4, 3), thr, 0, stream>>>(a);
  }
  dt_scores4<<<dim3(512), thr, 0, stream>>>(Q4h, Qp0, S0s);
  dt_prep4<<<dim3(128), thr, 0, stream>>>(S0s, Pfx);
  dt_sm_pv4<<<dim3(512), thr, 0, stream>>>(S0s, Pfx, Vp0, gam4, ksc, O4);
  {
    Gemm4 a = {{{O4, Wo4, bo4, OW4, 16384}, {O4, Wo4, bo4, OW4, 16384},
                {O4, Wo4, bo4, OW4, 16384}, {O4, Wo4, bo4, OW4, 16384}}};
    dt_gemmN<<<dim3(256, 4, 1), thr, 0, stream>>>(a);
  }
  dt_ln4w<<<dim3(4096), thr, 0, stream>>>(know, OW4, lng4, lnb4, zout);
}

// Round 5
// 516.107 us; speedup vs baseline: 1.8580x; 1.0269x over previous
//
#include <hip/hip_runtime.h>
#include <math.h>

#define SEQL 256
#define DM   256
#define NH   8
#define DKH  32
#define BSZ  4
#define NKN  16

// ---------------- wave (64-lane) helpers ----------------
__device__ __forceinline__ float wave_red_sum(float v) {
#pragma unroll
  for (int o = 32; o > 0; o >>= 1) v += __shfl_xor(v, o);
  return v;
}
__device__ __forceinline__ float wave_red_max(float v) {
#pragma unroll
  for (int o = 32; o > 0; o >>= 1) v = fmaxf(v, __shfl_xor(v, o));
  return v;
}
__device__ __forceinline__ float wave_incl_scan(float v) {
  const int lane = threadIdx.x & 63;
#pragma unroll
  for (int o = 1; o < 64; o <<= 1) {
    float u = __shfl_up(v, o);
    if (lane >= o) v += u;
  }
  return v;
}

// ---------------- multi-set GEMM: C[M,256] = A[M,256] @ W[256,256] + bias ----------------
struct GemmSet { const float* A; const float* W; const float* bias; float* C; int M; };
struct Gemm4 { GemmSet s[4]; };

__global__ __launch_bounds__(256) void dt_gemmN(Gemm4 args) {
  const GemmSet g = args.s[blockIdx.z];
  const int bm = blockIdx.x * 64, bn = blockIdx.y * 64;
  if (bm >= g.M) return;
  __shared__ float As[16][68];
  __shared__ float Bs[16][68];
  const int tid = threadIdx.x;
  const int tc = tid & 15, tr = tid >> 4;
  float acc[4][4] = {};
  for (int k0 = 0; k0 < DM; k0 += 16) {
    {
      const int m = tid >> 2, kq = tid & 3;
      int row = bm + m; row = row < g.M ? row : (g.M - 1);
      const float4 v = *reinterpret_cast<const float4*>(&g.A[(size_t)row * DM + k0 + kq * 4]);
      As[kq * 4 + 0][m] = v.x; As[kq * 4 + 1][m] = v.y;
      As[kq * 4 + 2][m] = v.z; As[kq * 4 + 3][m] = v.w;
    }
    {
      const int k = tid >> 4, nq = tid & 15;
      const float4 v = *reinterpret_cast<const float4*>(&g.W[(size_t)(k0 + k) * DM + bn + nq * 4]);
      *reinterpret_cast<float4*>(&Bs[k][nq * 4]) = v;
    }
    __syncthreads();
#pragma unroll
    for (int k = 0; k < 16; ++k) {
      float a[4], b[4];
#pragma unroll
      for (int i = 0; i < 4; ++i) a[i] = As[k][tr * 4 + i];
#pragma unroll
      for (int j = 0; j < 4; ++j) b[j] = Bs[k][tc * 4 + j];
#pragma unroll
      for (int i = 0; i < 4; ++i)
#pragma unroll
        for (int j = 0; j < 4; ++j) acc[i][j] = fmaf(a[i], b[j], acc[i][j]);
    }
    __syncthreads();
  }
#pragma unroll
  for (int i = 0; i < 4; ++i) {
    const int row = bm + tr * 4 + i;
    if (row >= g.M) continue;
    float4 o;
    o.x = acc[i][0] + g.bias[bn + tc * 4 + 0];
    o.y = acc[i][1] + g.bias[bn + tc * 4 + 1];
    o.z = acc[i][2] + g.bias[bn + tc * 4 + 2];
    o.w = acc[i][3] + g.bias[bn + tc * 4 + 3];
    *reinterpret_cast<float4*>(&g.C[(size_t)row * DM + bn + tc * 4]) = o;
  }
}

// ---------------- blocks 1-3 scores (2-set) ----------------
__global__ __launch_bounds__(256) void dt_scores_nt2(const float* __restrict__ Q0,
                                                     const float* __restrict__ Q1,
                                                     float* __restrict__ Sa,
                                                     float* __restrict__ Sb) {
  const int z = blockIdx.z;
  const int set = z >> 5, bh = z & 31;
  const float* Qp = set ? Q1 : Q0;
  float* S = set ? Sb : Sa;
  const int b = bh >> 3, h = bh & 7;
  const float* Q = Qp + (size_t)b * SEQL * DM + h * DKH;
  __shared__ float Qs[16][33], Ks[16][33];
  const int tid = threadIdx.x;
  const int tj = tid & 15, ti = tid >> 4;
  const int i0 = blockIdx.x * 16, j0 = blockIdx.y * 16;
  const int r = tid >> 5, c = tid & 31;
  Qs[r][c]     = Q[(size_t)(i0 + r) * DM + c];
  Qs[r + 8][c] = Q[(size_t)(i0 + 8 + r) * DM + c];
  Ks[r][c]     = Q[(size_t)(j0 + r) * DM + c];
  Ks[r + 8][c] = Q[(size_t)(j0 + 8 + r) * DM + c];
  __syncthreads();
  float acc = 0.f;
#pragma unroll
  for (int k = 0; k < DKH; ++k) acc = fmaf(Qs[ti][k], Ks[tj][k], acc);
  S[((size_t)bh * SEQL + i0 + ti) * SEQL + j0 + tj] = acc * 0.17677669529663687f;
}

// ---------------- block 4 base scores (i-independent) ----------------
__global__ __launch_bounds__(256) void dt_scores4(const float* __restrict__ Q4h,
                                                  const float* __restrict__ Kp,
                                                  float* __restrict__ S0) {
  const int idx = blockIdx.x * 256 + threadIdx.x;  // ((b*16+nk)*8+h)*256 + j
  const int j = idx & 255;
  const int h = (idx >> 8) & 7;
  const int nk = (idx >> 11) & 15;
  const int b = idx >> 15;
  const float* q = Q4h + nk * DM + h * DKH;
  const float* k = Kp + ((size_t)(b * SEQL + j)) * DM + h * DKH;
  float acc = 0.f;
#pragma unroll
  for (int c = 0; c < DKH; ++c) acc = fmaf(q[c], k[c], acc);
  S0[idx] = acc * 0.17677669529663687f;
}

// ---------------- block 4 prefix precompute ----------------
__global__ __launch_bounds__(256) void dt_prep4(const float* __restrict__ S0,
                                                float* __restrict__ Pfx) {
  const int wid = threadIdx.x >> 6, lane = threadIdx.x & 63;
  const int row = blockIdx.x * 4 + wid;
  const float4 s4 = *reinterpret_cast<const float4*>(S0 + (size_t)row * SEQL + lane * 4);
  float s[4] = {s4.x, s4.y, s4.z, s4.w};
  float mx = fmaxf(fmaxf(s[0], s[1]), fmaxf(s[2], s[3]));
  mx = wave_red_max(mx);
  float e[4], t = 0.f;
#pragma unroll
  for (int q = 0; q < 4; ++q) { e[q] = __expf(s[q] - mx); t += e[q]; }
  const float incl = wave_incl_scan(t);
  float run = incl - t;
  float4 o;
  run += e[0]; o.x = run;
  run += e[1]; o.y = run;
  run += e[2]; o.z = run;
  run += e[3]; o.w = run;
  *reinterpret_cast<float4*>(Pfx + (size_t)row * SEQL + lane * 4) = o;
}

// ---------------- decay-softmax blocks 1-3 (2-set), wave-per-row ----------------
__global__ __launch_bounds__(256) void dt_softmax13w2(const float* __restrict__ Sa,
                                                      const float* __restrict__ Sb,
                                                      float* __restrict__ Pa,
                                                      float* __restrict__ Pb,
                                                      const float* __restrict__ g0,
                                                      const float* __restrict__ g1) {
  const int wid = threadIdx.x >> 6, lane = threadIdx.x & 63;
  const int grow = blockIdx.x * 4 + wid;
  const int set = grow >> 13;
  const int row = grow & 8191;
  const float* S = set ? Sb : Sa;
  float* P = set ? Pb : Pa;
  const float* gam = set ? g1 : g0;
  const int i = row & 255, h = (row >> 8) & 7;
  const float g = -fabsf(gam[h]);
  const int jb = lane * 4;
  const float4 s4 = *reinterpret_cast<const float4*>(S + (size_t)row * SEQL + jb);
  float s[4] = {s4.x, s4.y, s4.z, s4.w};
  float mx = -1e30f;
#pragma unroll
  for (int q = 0; q < 4; ++q) if (jb + q <= i) mx = fmaxf(mx, s[q]);
  mx = wave_red_max(mx);
  float e[4], t = 0.f;
#pragma unroll
  for (int q = 0; q < 4; ++q) { e[q] = (jb + q <= i) ? __expf(s[q] - mx) : 0.f; t += e[q]; }
  const float incl = wave_incl_scan(t);
  const float total = __shfl(incl, 63);
  const float inv = 1.f / total;
  float run = incl - t;
  float p2[4], t2 = 0.f;
#pragma unroll
  for (int q = 0; q < 4; ++q) {
    run += e[q];
    const float cum = run * inv;
    float dd = (1.f - cum) * (float)(i - jb - q);
    dd = dd > 0.f ? dd : 0.f;
    float eff = __expf(g * sqrtf(dd));
    eff = fmaxf(eff, 1e-5f);
    const float y = s[q] * eff;
    p2[q] = (jb + q <= i) ? __expf(y) : 0.f;
    t2 += p2[q];
  }
  const float sum2 = wave_red_sum(t2);
  const float inv2 = 1.f / sum2;
  float4 o = {p2[0] * inv2, p2[1] * inv2, p2[2] * inv2, p2[3] * inv2};
  *reinterpret_cast<float4*>(P + (size_t)row * SEQL + jb) = o;
}

// ---------------- fused decay-softmax + PV, block 4 (register-blocked PV) ----------------
// one block per (b,nk,h): writes k_scores[b,h,:,nk,:] and O4[(b*16+nk)*256+i, h*32+c]
__global__ __launch_bounds__(256) void dt_sm_pv4(const float* __restrict__ S0,
                                                 const float* __restrict__ Pfx,
                                                 const float* __restrict__ Vp,
                                                 const float* __restrict__ gam,
                                                 float* __restrict__ KS,
                                                 float* __restrict__ O) {
  __shared__ float Vs[256][32];   // V slice, [j][c]
  __shared__ float Pl[32][268];   // P rows for one 32-i chunk (stride 268: bank spread)
  __shared__ float Pfl[256];      // prefix row
  const int z = blockIdx.x;       // (b*16+nk)*8+h
  const int h = z & 7, b = z >> 7;
  const int nk = (z >> 3) & 15, bnk = z >> 3;
  const int tid = threadIdx.x, lane = tid & 63, w = tid >> 6;
  const float* Vbase = Vp + (size_t)b * SEQL * DM + h * DKH;
  {
    const int j = tid >> 3, c4 = (tid & 7) * 4;
    for (int jj = 0; jj < 256; jj += 32) {
      const float4 v = *reinterpret_cast<const float4*>(Vbase + (size_t)(jj + j) * DM + c4);
      *reinterpret_cast<float4*>(&Vs[jj + j][c4]) = v;
    }
  }
  if (tid < 64) {
    const float4 p = *reinterpret_cast<const float4*>(Pfx + (size_t)z * SEQL + tid * 4);
    *reinterpret_cast<float4*>(&Pfl[tid * 4]) = p;
  }
  const float4 s4 = *reinterpret_cast<const float4*>(S0 + (size_t)z * SEQL + lane * 4);
  const float4 p4 = *reinterpret_cast<const float4*>(Pfx + (size_t)z * SEQL + lane * 4);
  const float s[4] = {s4.x, s4.y, s4.z, s4.w};
  const float pj[4] = {p4.x, p4.y, p4.z, p4.w};
  const float g = -fabsf(gam[h]);
  const int jb = lane * 4;
  // PV ownership: 4 rows x 4 cols per thread, j-quartered across lanes
  const int r0 = tid >> 5, cg = tid & 7, jq = (tid >> 3) & 3;
  __syncthreads();

  for (int chunk = 0; chunk < 8; ++chunk) {
    const int i0 = chunk * 32;
#pragma unroll
    for (int r = 0; r < 8; ++r) {
      const int il = w * 8 + r;
      const int i = i0 + il;
      float pv[4];
      if (i == 0) {
        pv[0] = pv[1] = pv[2] = pv[3] = 0.f;
      } else {
        const float rinv = 1.f / Pfl[i - 1];
        float t = 0.f, m = 0.f;
#pragma unroll
        for (int q = 0; q < 4; ++q) {
          const float cum = pj[q] * rinv;
          float dd = (1.f - cum) * (float)(i - jb - q);
          dd = dd > 0.f ? dd : 0.f;
          float eff = __expf(g * sqrtf(dd));
          eff = fmaxf(eff, 1e-5f);
          const float y = s[q] * eff;
          pv[q] = (jb + q < i) ? __expf(y) : 0.f;
          t += pv[q];
          m = fmaxf(m, pv[q]);
        }
#pragma unroll
        for (int o = 32; o > 0; o >>= 1) {
          t += __shfl_xor(t, o);
          m = fmaxf(m, __shfl_xor(m, o));
        }
        const float inv2 = 1.f / t;
        const float scale = fminf(1.f / (m * inv2 + 1e-8f), 5.f);
        const float f = inv2 * scale;
        pv[0] *= f; pv[1] *= f; pv[2] *= f; pv[3] *= f;
      }
      const float4 o4 = {pv[0], pv[1], pv[2], pv[3]};
      *reinterpret_cast<float4*>(KS + ((((size_t)(b * NH + h)) * SEQL + i) * NKN + nk) * SEQL + jb) = o4;
      *reinterpret_cast<float4*>(&Pl[il][jb]) = o4;
    }
    __syncthreads();
    // register-blocked PV: 64 FMA per 8 LDS b128 reads
    float4 acc[4] = {{0.f,0.f,0.f,0.f},{0.f,0.f,0.f,0.f},{0.f,0.f,0.f,0.f},{0.f,0.f,0.f,0.f}};
#pragma unroll 4
    for (int t4 = 0; t4 < 16; ++t4) {
      const int jb2 = t4 * 16 + jq * 4;
      float pr[4][4];
#pragma unroll
      for (int r = 0; r < 4; ++r) {
        const float4 p = *reinterpret_cast<const float4*>(&Pl[r0 * 4 + r][jb2]);
        pr[r][0] = p.x; pr[r][1] = p.y; pr[r][2] = p.z; pr[r][3] = p.w;
      }
#pragma unroll
      for (int k = 0; k < 4; ++k) {
        const float4 v = *reinterpret_cast<const float4*>(&Vs[jb2 + k][cg * 4]);
#pragma unroll
        for (int r = 0; r < 4; ++r) {
          acc[r].x = fmaf(pr[r][k], v.x, acc[r].x);
          acc[r].y = fmaf(pr[r][k], v.y, acc[r].y);
          acc[r].z = fmaf(pr[r][k], v.z, acc[r].z);
          acc[r].w = fmaf(pr[r][k], v.w, acc[r].w);
        }
      }
    }
#pragma unroll
    for (int r = 0; r < 4; ++r) {
      acc[r].x += __shfl_xor(acc[r].x, 8);  acc[r].x += __shfl_xor(acc[r].x, 16);
      acc[r].y += __shfl_xor(acc[r].y, 8);  acc[r].y += __shfl_xor(acc[r].y, 16);
      acc[r].z += __shfl_xor(acc[r].z, 8);  acc[r].z += __shfl_xor(acc[r].z, 16);
      acc[r].w += __shfl_xor(acc[r].w, 8);  acc[r].w += __shfl_xor(acc[r].w, 16);
    }
    if ((tid & 24) == 0) {
#pragma unroll
      for (int r = 0; r < 4; ++r)
        *reinterpret_cast<float4*>(O + ((size_t)(bnk * SEQL + i0 + r0 * 4 + r)) * DM + h * DKH + cg * 4) = acc[r];
    }
    __syncthreads();  // Pl reused next chunk
  }
}

// ---------------- PV blocks 1-3 (2-set), register-blocked ----------------
// block = (i-chunk, z); z = set*32 + bh
__global__ __launch_bounds__(256) void dt_pv13_2(const float* __restrict__ Pa,
                                                 const float* __restrict__ Pb,
                                                 const float* __restrict__ V0,
                                                 const float* __restrict__ V1,
                                                 float* __restrict__ Oa,
                                                 float* __restrict__ Ob) {
  __shared__ float Vs[256][32];
  __shared__ float Pl[32][268];
  const int z = blockIdx.y;
  const int set = z >> 5, bh = z & 31;
  const float* P = set ? Pb : Pa;
  const float* Vp = set ? V1 : V0;
  float* O = set ? Ob : Oa;
  const int b = bh >> 3, h = bh & 7;
  const int i0 = blockIdx.x * 32;
  const int tid = threadIdx.x;
  const float* Prow = P + ((size_t)bh * SEQL + i0) * SEQL;
  const float* Vbase = Vp + (size_t)b * SEQL * DM + h * DKH;
  // stage V[256][32] and P[32][256], both coalesced
#pragma unroll
  for (int t = 0; t < 8; ++t) {
    const int idx = t * 256 + tid;
    const int j = idx >> 3, c4 = (idx & 7) * 4;
    *reinterpret_cast<float4*>(&Vs[j][c4]) =
        *reinterpret_cast<const float4*>(Vbase + (size_t)j * DM + c4);
    const int prw = idx >> 6, pc4 = (idx & 63) * 4;
    *reinterpret_cast<float4*>(&Pl[prw][pc4]) =
        *reinterpret_cast<const float4*>(Prow + (size_t)prw * SEQL + pc4);
  }
  __syncthreads();
  const int r0 = tid >> 5, cg = tid & 7, jq = (tid >> 3) & 3;
  float4 acc[4] = {{0.f,0.f,0.f,0.f},{0.f,0.f,0.f,0.f},{0.f,0.f,0.f,0.f},{0.f,0.f,0.f,0.f}};
#pragma unroll 4
  for (int t4 = 0; t4 < 16; ++t4) {
    const int jb2 = t4 * 16 + jq * 4;
    float pr[4][4];
#pragma unroll
    for (int r = 0; r < 4; ++r) {
      const float4 p = *reinterpret_cast<const float4*>(&Pl[r0 * 4 + r][jb2]);
      pr[r][0] = p.x; pr[r][1] = p.y; pr[r][2] = p.z; pr[r][3] = p.w;
    }
#pragma unroll
    for (int k = 0; k < 4; ++k) {
      const float4 v = *reinterpret_cast<const float4*>(&Vs[jb2 + k][cg * 4]);
#pragma unroll
      for (int r = 0; r < 4; ++r) {
        acc[r].x = fmaf(pr[r][k], v.x, acc[r].x);
        acc[r].y = fmaf(pr[r][k], v.y, acc[r].y);
        acc[r].z = fmaf(pr[r][k], v.z, acc[r].z);
        acc[r].w = fmaf(pr[r][k], v.w, acc[r].w);
      }
    }
  }
#pragma unroll
  for (int r = 0; r < 4; ++r) {
    acc[r].x += __shfl_xor(acc[r].x, 8);  acc[r].x += __shfl_xor(acc[r].x, 16);
    acc[r].y += __shfl_xor(acc[r].y, 8);  acc[r].y += __shfl_xor(acc[r].y, 16);
    acc[r].z += __shfl_xor(acc[r].z, 8);  acc[r].z += __shfl_xor(acc[r].z, 16);
    acc[r].w += __shfl_xor(acc[r].w, 8);  acc[r].w += __shfl_xor(acc[r].w, 16);
  }
  if ((tid & 24) == 0) {
#pragma unroll
    for (int r = 0; r < 4; ++r)
      *reinterpret_cast<float4*>(O + ((size_t)(b * SEQL + i0 + r0 * 4 + r)) * DM + h * DKH + cg * 4) = acc[r];
  }
}

// ---------------- residual + LayerNorm (2-set), wave-per-row ----------------
__global__ __launch_bounds__(256) void dt_ln_res2(const float* __restrict__ X0,
                                                  const float* __restrict__ X1,
                                                  const float* __restrict__ Y0,
                                                  const float* __restrict__ Y1,
                                                  const float* __restrict__ G0,
                                                  const float* __restrict__ G1,
                                                  const float* __restrict__ B0,
                                                  const float* __restrict__ B1,
                                                  float* __restrict__ Z0,
                                                  float* __restrict__ Z1) {
  const int wid = threadIdx.x >> 6, lane = threadIdx.x & 63;
  const int grow = blockIdx.x * 4 + wid;
  const int set = grow >> 10;
  const int row = grow & 1023;
  const float* X = set ? X1 : X0;
  const float* Y = set ? Y1 : Y0;
  const float* g = set ? G1 : G0;
  const float* bb = set ? B1 : B0;
  float* Z = set ? Z1 : Z0;
  const int jb = lane * 4;
  const float4 x4 = *reinterpret_cast<const float4*>(X + (size_t)row * DM + jb);
  const float4 y4 = *reinterpret_cast<const float4*>(Y + (size_t)row * DM + jb);
  float x[4] = {x4.x + y4.x, x4.y + y4.y, x4.z + y4.z, x4.w + y4.w};
  const float mean = wave_red_sum(x[0] + x[1] + x[2] + x[3]) * (1.f / 256.f);
  float vs = 0.f;
#pragma unroll
  for (int q = 0; q < 4; ++q) { const float d = x[q] - mean; vs += d * d; }
  const float var = wave_red_sum(vs) * (1.f / 256.f);
  const float rstd = 1.f / sqrtf(var + 1e-5f);
  const float4 g4 = *reinterpret_cast<const float4*>(g + jb);
  const float4 b4 = *reinterpret_cast<const float4*>(bb + jb);
  float4 o;
  o.x = (x[0] - mean) * rstd * g4.x + b4.x;
  o.y = (x[1] - mean) * rstd * g4.y + b4.y;
  o.z = (x[2] - mean) * rstd * g4.z + b4.z;
  o.w = (x[3] - mean) * rstd * g4.w + b4.w;
  *reinterpret_cast<float4*>(Z + (size_t)row * DM + jb) = o;
}

// ---------------- residual + LayerNorm block 4 ----------------
__global__ __launch_bounds__(256) void dt_ln4w(const float* __restrict__ know,
                                               const float* __restrict__ Y,
                                               const float* __restrict__ g,
                                               const float* __restrict__ bb,
                                               float* __restrict__ Z) {
  const int wid = threadIdx.x >> 6, lane = threadIdx.x & 63;
  const int row = blockIdx.x * 4 + wid;  // (b*16+nk)*256 + i
  const int i = row & 255;
  const int nk = (row >> 8) & 15;
  const int b = row >> 12;
  const int jb = lane * 4;
  const float4 k4 = *reinterpret_cast<const float4*>(know + (size_t)nk * DM + jb);
  const float4 y4 = *reinterpret_cast<const float4*>(Y + (size_t)row * DM + jb);
  float x[4] = {k4.x + y4.x, k4.y + y4.y, k4.z + y4.z, k4.w + y4.w};
  const float mean = wave_red_sum(x[0] + x[1] + x[2] + x[3]) * (1.f / 256.f);
  float vs = 0.f;
#pragma unroll
  for (int q = 0; q < 4; ++q) { const float d = x[q] - mean; vs += d * d; }
  const float var = wave_red_sum(vs) * (1.f / 256.f);
  const float rstd = 1.f / sqrtf(var + 1e-5f);
  const float4 g4 = *reinterpret_cast<const float4*>(g + jb);
  const float4 b4 = *reinterpret_cast<const float4*>(bb + jb);
  float4 o;
  o.x = (x[0] - mean) * rstd * g4.x + b4.x;
  o.y = (x[1] - mean) * rstd * g4.y + b4.y;
  o.z = (x[2] - mean) * rstd * g4.z + b4.z;
  o.w = (x[3] - mean) * rstd * g4.w + b4.w;
  *reinterpret_cast<float4*>(Z + ((size_t)(b * SEQL + i)) * (NKN * DM) + (size_t)nk * DM + jb) = o;
}

// ---------------- launcher ----------------
extern "C" void kernel_launch(void* const* d_in, const int* in_sizes, int n_in,
                              void* d_out, int out_size, void* d_ws, size_t ws_size,
                              hipStream_t stream) {
  (void)in_sizes; (void)n_in; (void)out_size; (void)ws_size;
  const float* q_emb = (const float*)d_in[0];
  const float* s_emb = (const float*)d_in[1];
  const float* know  = (const float*)d_in[3];
  const float* Wq1 = (const float*)d_in[4],  *bq1 = (const float*)d_in[5];
  const float* Wv1 = (const float*)d_in[6],  *bv1 = (const float*)d_in[7];
  const float* Wo1 = (const float*)d_in[8],  *bo1 = (const float*)d_in[9];
  const float* gam1 = (const float*)d_in[10], *lng1 = (const float*)d_in[11], *lnb1 = (const float*)d_in[12];
  const float* Wq2 = (const float*)d_in[13], *bq2 = (const float*)d_in[14];
  const float* Wv2 = (const float*)d_in[15], *bv2 = (const float*)d_in[16];
  const float* Wo2 = (const float*)d_in[17], *bo2 = (const float*)d_in[18];
  const float* gam2 = (const float*)d_in[19], *lng2 = (const float*)d_in[20], *lnb2 = (const float*)d_in[21];
  const float* Wq3 = (const float*)d_in[22], *bq3 = (const float*)d_in[23];
  const float* Wv3 = (const float*)d_in[24], *bv3 = (const float*)d_in[25];
  const float* Wo3 = (const float*)d_in[26], *bo3 = (const float*)d_in[27];
  const float* gam3 = (const float*)d_in[28], *lng3 = (const float*)d_in[29], *lnb3 = (const float*)d_in[30];
  const float* Wq4 = (const float*)d_in[31], *bq4 = (const float*)d_in[32];
  const float* Wk4 = (const float*)d_in[33], *bk4 = (const float*)d_in[34];
  const float* Wv4 = (const float*)d_in[35], *bv4 = (const float*)d_in[36];
  const float* Wo4 = (const float*)d_in[37], *bo4 = (const float*)d_in[38];
  const float* gam4 = (const float*)d_in[39], *lng4 = (const float*)d_in[40], *lnb4 = (const float*)d_in[41];

  // workspace: 28 units of 262144 floats (28 MB)
  float* ws = (float*)d_ws;
  const size_t U = 262144;
  float* Qp0 = ws + 0 * U;           // also Qp3, Kp4
  float* Qp1 = ws + 1 * U;
  float* Vp0 = ws + 2 * U;           // also Vp3, Vp4
  float* Vp1 = ws + 3 * U;
  float* Sa  = ws + 4 * U;           // 8U (b12 set0, b3); b4: OW4 (16U)
  float* Sb  = ws + 12 * U;          // 8U
  float* O0  = ws + 20 * U;          // also O3, then Pfx (b4)
  float* O1  = ws + 21 * U;
  float* OW0 = ws + 22 * U;          // also OW3
  float* OW1 = ws + 23 * U;
  float* hq  = ws + 24 * U;
  float* hs  = ws + 25 * U;
  float* pbf = ws + 26 * U;
  float* Q4h = ws + 27 * U;          // 4096
  float* S0s = Q4h + 4096;           // 131072
  float* OW4 = Sa;                   // 16U (Sa..Sb dead in block 4)
  float* Pfx = O0;                   // dead after block-3 out-proj

  float* zout = (float*)d_out;
  float* qsc  = zout + 4194304;
  float* ksc  = qsc + 2097152;
  float* O4   = zout;                // scratch; ln4w fully rewrites zout at the end

  const dim3 thr(256);

  // ---- blocks 1+2 batched ----
  {
    Gemm4 a = {{{q_emb, Wq1, bq1, Qp0, 1024}, {q_emb, Wv1, bv1, Vp0, 1024},
                {s_emb, Wq2, bq2, Qp1, 1024}, {s_emb, Wv2, bv2, Vp1, 1024}}};
    dt_gemmN<<<dim3(16, 4, 4), thr, 0, stream>>>(a);
  }
  dt_scores_nt2<<<dim3(16, 16, 64), thr, 0, stream>>>(Qp0, Qp1, Sa, Sb);
  dt_softmax13w2<<<dim3(4096), thr, 0, stream>>>(Sa, Sb, Sa, Sb, gam1, gam2);
  dt_pv13_2<<<dim3(8, 64), thr, 0, stream>>>(Sa, Sb, Vp0, Vp1, O0, O1);
  {
    Gemm4 a = {{{O0, Wo1, bo1, OW0, 1024}, {O1, Wo2, bo2, OW1, 1024},
                {O0, Wo1, bo1, OW0, 1024}, {O1, Wo2, bo2, OW1, 1024}}};
    dt_gemmN<<<dim3(16, 4, 2), thr, 0, stream>>>(a);
  }
  dt_ln_res2<<<dim3(512), thr, 0, stream>>>(q_emb, s_emb, OW0, OW1, lng1, lng2, lnb1, lnb2, hq, hs);

  // ---- block 3 (q=k=hq, v=hs -> pbf; scores -> q_scores out) ----
  {
    Gemm4 a = {{{hq, Wq3, bq3, Qp0, 1024}, {hs, Wv3, bv3, Vp0, 1024},
                {hq, Wq3, bq3, Qp0, 1024}, {hs, Wv3, bv3, Vp0, 1024}}};
    dt_gemmN<<<dim3(16, 4, 2), thr, 0, stream>>>(a);
  }
  dt_scores_nt2<<<dim3(16, 16, 32), thr, 0, stream>>>(Qp0, Qp0, Sa, Sa);
  dt_softmax13w2<<<dim3(2048), thr, 0, stream>>>(Sa, Sa, qsc, qsc, gam3, gam3);
  dt_pv13_2<<<dim3(8, 32), thr, 0, stream>>>(qsc, qsc, Vp0, Vp0, O0, O0);
  {
    Gemm4 a = {{{O0, Wo3, bo3, OW0, 1024}, {O0, Wo3, bo3, OW0, 1024},
                {O0, Wo3, bo3, OW0, 1024}, {O0, Wo3, bo3, OW0, 1024}}};
    dt_gemmN<<<dim3(16, 4, 1), thr, 0, stream>>>(a);
  }
  dt_ln_res2<<<dim3(256), thr, 0, stream>>>(hq, hq, OW0, OW0, lng3, lng3, lnb3, lnb3, pbf, pbf);

  // ---- block 4 ----
  {
    Gemm4 a = {{{hq, Wk4, bk4, Qp0, 1024}, {pbf, Wv4, bv4, Vp0, 1024},
                {know, Wq4, bq4, Q4h, 16}, {know, Wq4, bq4, Q4h, 16}}};
    dt_gemmN<<<dim3(16, 4, 3), thr, 0, stream>>>(a);
  }
  dt_scores4<<<dim3(512), thr, 0, stream>>>(Q4h, Qp0, S0s);
  dt_prep4<<<dim3(128), thr, 0, stream>>>(S0s, Pfx);
  dt_sm_pv4<<<dim3(512), thr, 0, stream>>>(S0s, Pfx, Vp0, gam4, ksc, O4);
  {
    Gemm4 a = {{{O4, Wo4, bo4, OW4, 16384}, {O4, Wo4, bo4, OW4, 16384},
                {O4, Wo4, bo4, OW4, 16384}, {O4, Wo4, bo4, OW4, 16384}}};
    dt_gemmN<<<dim3(256, 4, 1), thr, 0, stream>>>(a);
  }
  dt_ln4w<<<dim3(4096), thr, 0, stream>>>(know, OW4, lng4, lnb4, zout);
}